// Round 4
// baseline (1873.758 us; speedup 1.0000x reference)
//
#include <hip/hip_runtime.h>

// ============================================================================
// DecoderGenerator: 2-layer LSTM decoder + additive attention + big vocab
// projection + NLL, fully fused on-device.
//
//   1. prep_kernel     : bf16-cast weights/enc/fcW, gather embeddings,
//                        transpose enc, init h-state buffers, zero flags.
//   2. a0_kernel       : A0T[t][col][b] = xs @ W_ih0^T + b  (transposed store)
//   3. lstm_kernel     : persistent 32-WG x 512-thread kernel, 129 ticks.
//                        ROUND 9: coupled halves (round-1 structure) with RAW
//                        s_barriers (no implicit vmcnt(0) drains), counted
//                        vmcnt publish waits, conflict-free staging (HPAD=516,
//                        lane-consecutive 8B), transposed A0 (1 coalesced
//                        load), split MFMA chains.
//   4. phpe_kernel     : ph = Hall@Wh^T ; pe = enc@We^T + attn_b
//   5. logits_kernel   : logits[t,b,l] = sum_k v_w[k] tanh(ph+pe)
//   6. att_kernel      : softmax over b (axis=1 of (T,B,L) — per reference!)
//   7. weighted_kernel : weighted = att @ enc  (per-batch GEMM) -> G[:,512:]
//   8. fc_kernel       : m97-structure 128x128xBK64 tiled GEMM + fused
//                        per-row (max,sumexp) partials.
//   9. tgt_kernel      : target logits z_y per row
//  10. finalize_kernel : logsumexp merge + masked-mean NLL -> d_out[0]
// ============================================================================

#define DI __device__ __forceinline__

typedef __attribute__((ext_vector_type(8))) short short8;
typedef __attribute__((ext_vector_type(4))) float floatx4;
typedef unsigned long long ull;

#define TSEQ   128
#define VOCAB  32000
#define GDIM   2048   // 4*H
#define NROW   2048   // B*T
#define KFC    1024   // 2*H
#define HPAD   516    // LDS row stride: 516*2B/4 = 258 ≡ 2 (mod 32) -> rows
                      // 0..15 hit distinct even banks; b128 frag reads run at
                      // the 8-clock minimum (no excess conflict)

// ---------------- small helpers ----------------
DI float bf2f(unsigned short u) {
    union { unsigned u; float f; } x; x.u = ((unsigned)u) << 16; return x.f;
}
DI unsigned short f2bf(float f) {   // RNE float -> bf16
    unsigned u = __float_as_uint(f);
    unsigned r = (u + 0x7FFF + ((u >> 16) & 1)) >> 16;
    return (unsigned short)r;
}
DI short8 ld8(const unsigned short* p) { return *(const short8*)p; }
DI floatx4 mfma16(short8 a, short8 b, floatx4 c) {
    return __builtin_amdgcn_mfma_f32_16x16x32_bf16(a, b, c, 0, 0, 0);
}
DI float sigm(float x) { return __builtin_amdgcn_rcpf(1.f + __expf(-x)); }
DI float tanh_f(float x) {
    float xc = fminf(8.f, fmaxf(-8.f, x));
    float e  = __expf(2.f * xc);
    return (e - 1.f) * __builtin_amdgcn_rcpf(e + 1.f);
}

// async global -> LDS, 16B per lane. LDS dest must be wave-uniform base;
// lane l writes base + l*16. Global src is per-lane.
#define GLD16(gsrc, ldst)                                                     \
    __builtin_amdgcn_global_load_lds(                                         \
        (const __attribute__((address_space(1))) unsigned int*)(gsrc),        \
        (__attribute__((address_space(3))) unsigned int*)(ldst), 16, 0, 0)

// fallback path: make the failure visible instead of faulting
__global__ void zero_out_kernel(float* out, int n) {
    int i = blockIdx.x * 64 + threadIdx.x;
    if (i < n) out[i] = 0.f;
}

// ============================================================================
// 1. prep kernel : segmented grid-stride over all conversion jobs
// ============================================================================
__global__ void prep_kernel(const int* X, const float* enc, const float* emb,
                            const float* Wih0, const float* Whh0,
                            const float* Wih1, const float* Whh1,
                            const float* attnW, const float* h0,
                            const float* fcW,
                            unsigned short* wih0b, unsigned short* whh0b,
                            unsigned short* wih1b, unsigned short* whh1b,
                            unsigned short* whb, unsigned short* web,
                            unsigned short* encb, unsigned short* enctb,
                            unsigned short* xsb,
                            unsigned short* h0buf, unsigned short* h1buf,
                            unsigned short* fcWb,
                            int* ctrl) {
    if (blockIdx.x == 0) {              // zero all 3072 flag ints
#pragma unroll
        for (int j = 0; j < 12; ++j) ctrl[threadIdx.x + 256 * j] = 0;
    }
    long i = (long)blockIdx.x * 256 + threadIdx.x;
    const long NW = 1048576;
    const long NA = 262144;            // 512x512 half of attn_W
    if (i < NW) { wih0b[i] = f2bf(Wih0[i]); return; } i -= NW;
    if (i < NW) { whh0b[i] = f2bf(Whh0[i]); return; } i -= NW;
    if (i < NW) { wih1b[i] = f2bf(Wih1[i]); return; } i -= NW;
    if (i < NW) { whh1b[i] = f2bf(Whh1[i]); return; } i -= NW;
    if (i < NA) { long k = i >> 9, h = i & 511; whb[i] = f2bf(attnW[k * 1024 + h]);       return; } i -= NA;
    if (i < NA) { long k = i >> 9, h = i & 511; web[i] = f2bf(attnW[k * 1024 + 512 + h]); return; } i -= NA;
    if (i < NW) { encb[i] = f2bf(enc[i]); return; } i -= NW;
    if (i < NW) {  // enc_t[b][h][l] = enc[b][l][h]
        long b = i >> 16, r = i & 65535, h = r >> 7, l = r & 127;
        enctb[i] = f2bf(enc[(b * 128 + l) * 512 + h]); return;
    } i -= NW;
    if (i < NW) {  // xs[t*16+b][e] = emb[X[b][t]][e]
        long m = i >> 9, e = i & 511, t = m >> 4, b = m & 15;
        int xi = X[b * 129 + t];
        xi = (xi < 0) ? 0 : ((xi >= VOCAB) ? VOCAB - 1 : xi);   // defensive
        xsb[i] = f2bf(emb[(long)xi * 512 + e]); return;
    } i -= NW;
    if (i < 16384) {  // h inits into parity-1 buffers
        long layer = i >> 13, r = i & 8191;
        unsigned short v = f2bf(h0[layer * 8192 + r]);
        if (layer == 0) h0buf[8192 + r] = v; else h1buf[8192 + r] = v;
        return;
    } i -= 16384;
    if (i < 8192000) {  // fcW f32 -> bf16, 4 elements per thread
        float4 v = ((const float4*)fcW)[i];
        ushort4 o;
        o.x = f2bf(v.x); o.y = f2bf(v.y); o.z = f2bf(v.z); o.w = f2bf(v.w);
        ((ushort4*)fcWb)[i] = o;
    }
}

// ============================================================================
// shared 64x64 MFMA tile: C[m0..+63][n0..+63] += A(m,k) * B(n,k)^T
// ============================================================================
DI void gemm64_acc(const unsigned short* A, const unsigned short* Bw,
                   int m0, int n0, int lda, int ldb, int nkb, floatx4 acc[4]) {
    int tid = threadIdx.x;
    int wv = tid >> 6, ln = tid & 63;
    int colL = ln & 15, koff = (ln >> 4) * 8;
    const unsigned short* ar  = A  + (size_t)(m0 + wv * 16 + colL) * lda + koff;
    const unsigned short* br0 = Bw + (size_t)(n0 +  0 + colL) * ldb + koff;
    const unsigned short* br1 = Bw + (size_t)(n0 + 16 + colL) * ldb + koff;
    const unsigned short* br2 = Bw + (size_t)(n0 + 32 + colL) * ldb + koff;
    const unsigned short* br3 = Bw + (size_t)(n0 + 48 + colL) * ldb + koff;
    for (int kb = 0; kb < nkb; ++kb) {
        short8 af = ld8(ar + kb * 32);
        acc[0] = mfma16(af, ld8(br0 + kb * 32), acc[0]);
        acc[1] = mfma16(af, ld8(br1 + kb * 32), acc[1]);
        acc[2] = mfma16(af, ld8(br2 + kb * 32), acc[2]);
        acc[3] = mfma16(af, ld8(br3 + kb * 32), acc[3]);
    }
}

// 2. A0T[(t*GDIM + col)*16 + b] = (xs @ W_ih0^T)[t*16+b][col] + bias
//    (transposed so the lstm prefetch is one coalesced 8B load per lane)
__global__ void a0_kernel(const unsigned short* xs, const unsigned short* wih0b,
                          const float* bih0, const float* bhh0, unsigned short* A0T) {
    floatx4 acc[4] = {{0,0,0,0},{0,0,0,0},{0,0,0,0},{0,0,0,0}};
    int m0 = blockIdx.x * 64, n0 = blockIdx.y * 64;
    gemm64_acc(xs, wih0b, m0, n0, 512, 512, 16, acc);
    int tid = threadIdx.x, wv = tid >> 6, ln = tid & 63, colL = ln & 15, q = ln >> 4;
    int trow = (m0 >> 4) + wv;           // m rows are mrow..mrow+15 = one t
#pragma unroll
    for (int nt = 0; nt < 4; ++nt) {
        int col = n0 + nt * 16 + colL;
        float bb = bih0[col] + bhh0[col];
#pragma unroll
        for (int r = 0; r < 4; ++r)
            A0T[((size_t)trow * GDIM + col) * 16 + q * 4 + r] = f2bf(acc[nt][r] + bb);
    }
}

// ============================================================================
// 3. persistent LSTM kernel.  32 WGs x 512 threads.  ROUND 9.
//    Coupled halves, 4 RAW barriers/tick:
//      stage -> [lgkm0+bar] -> MFMA/gbuf -> [lgkm0+bar] -> elementwise +
//      h-store (+Hall/Gmat) -> counted vmcnt -> [bar] -> flag publish ->
//      poll -> [bar]
//    Counted vmcnt: h-store is the OLDEST outstanding vmem op at the wait;
//    vmcnt retires in issue order (m135), so vmcnt(1)/(2) guarantees the
//    h-store is LLC-acked while the A0 prefetch / Hall/Gmat acks stay in
//    flight across the publish+poll window.
// ============================================================================
__global__ __launch_bounds__(512, 1)
void lstm_kernel(const unsigned short* A0T,
                 const unsigned short* whh0b, const unsigned short* wih1b,
                 const unsigned short* whh1b,
                 const float* bih1, const float* bhh1, const float* c0in,
                 unsigned short* h0buf, unsigned short* h1buf,
                 unsigned short* Hall, unsigned short* Gmat, int* flags) {
    __shared__ unsigned short hsh0[16 * HPAD];   // h0[t-1], shared by both halves
    __shared__ unsigned short hsh1[16 * HPAD];   // h1[t-2], read by L1 half
    __shared__ float gbuf[2][4][16][17];         // [half][gate][batch][unit]
    int wg = blockIdx.x;            // 0..31
    int tid = threadIdx.x;          // 0..511
    int half = tid >> 8;            // 0 = L0, 1 = L1
    int lt   = tid & 255;
    int wv = lt >> 6, ln = lt & 63;
    int u0 = wg * 16;
    int n0 = wv * 512 + u0;         // gate column base (wave-of-half = gate)
    int colL = ln & 15, q = ln >> 4, koff = q * 8;
    int eb = lt >> 4, eu = lt & 15; // elementwise mapping within half
    float c = c0in[half * 8192 + eb * 512 + u0 + eu];
    float bias1 = (half == 1) ? (bih1[n0 + colL] + bhh1[n0 + colL]) : 0.f;

    // ---- one-time: weight slices into registers ----
    short8 wA[16], wB[16];
    if (half == 0) {
        const unsigned short* wr0 = whh0b + (size_t)(n0 + colL) * 512 + koff;
#pragma unroll
        for (int kb = 0; kb < 16; ++kb) wA[kb] = ld8(wr0 + kb * 32);
#pragma unroll
        for (int kb = 0; kb < 16; ++kb) wB[kb] = wA[kb];   // unused, keep defined
    } else {
        const unsigned short* wr1 = wih1b + (size_t)(n0 + colL) * 512 + koff;
        const unsigned short* wr2 = whh1b + (size_t)(n0 + colL) * 512 + koff;
#pragma unroll
        for (int kb = 0; kb < 16; ++kb) wA[kb] = ld8(wr1 + kb * 32);
#pragma unroll
        for (int kb = 0; kb < 16; ++kb) wB[kb] = ld8(wr2 + kb * 32);
    }

    // A0 prefetch for tick 0 (L0 half): one coalesced 8B load
    ull a0raw = 0;
    if (half == 0)
        a0raw = *(const ull*)(A0T + ((size_t)0 * GDIM + n0 + colL) * 16 + q * 4);

    __syncthreads();   // clean start (full drain once, outside the loop)

#pragma unroll 1
    for (int t = 0; t <= TSEQ; ++t) {
        bool actL1 = (t >= 1);
        bool act = half ? actL1 : (t < TSEQ);
        // ---- stage h vectors LLC -> LDS (lane-consecutive, conflict-free) ----
        {
            const ull* s0 = (const ull*)(h0buf + ((t - 1) & 1) * 8192);
            ull v0[4];
#pragma unroll
            for (int k = 0; k < 4; ++k)
                v0[k] = __hip_atomic_load(s0 + tid + 512 * k, __ATOMIC_RELAXED,
                                          __HIP_MEMORY_SCOPE_AGENT);
            ull v1[4];
            if (actL1) {
                const ull* s1 = (const ull*)(h1buf + ((t - 2) & 1) * 8192);
#pragma unroll
                for (int k = 0; k < 4; ++k)
                    v1[k] = __hip_atomic_load(s1 + tid + 512 * k, __ATOMIC_RELAXED,
                                              __HIP_MEMORY_SCOPE_AGENT);
            }
#pragma unroll
            for (int k = 0; k < 4; ++k) {
                int u = tid + 512 * k;
                *(ull*)&hsh0[(u >> 7) * HPAD + (u & 127) * 4] = v0[k];
            }
            if (actL1) {
#pragma unroll
                for (int k = 0; k < 4; ++k) {
                    int u = tid + 512 * k;
                    *(ull*)&hsh1[(u >> 7) * HPAD + (u & 127) * 4] = v1[k];
                }
            }
        }
        asm volatile("s_waitcnt lgkmcnt(0)" ::: "memory");
        asm volatile("s_barrier" ::: "memory");
        // ---- MFMA: LDS fragments x register weights (split chains) ----
        if (act) {
            floatx4 accv;
            const unsigned short* hl0 = hsh0 + colL * HPAD + koff;
            if (half == 0) {
                floatx4 c0v, c1v = {0, 0, 0, 0};
                c0v[0] = bf2f((unsigned short)(a0raw));
                c0v[1] = bf2f((unsigned short)(a0raw >> 16));
                c0v[2] = bf2f((unsigned short)(a0raw >> 32));
                c0v[3] = bf2f((unsigned short)(a0raw >> 48));
#pragma unroll
                for (int kb = 0; kb < 8; ++kb) {
                    c0v = mfma16(ld8(hl0 + (2 * kb) * 32),     wA[2 * kb],     c0v);
                    c1v = mfma16(ld8(hl0 + (2 * kb + 1) * 32), wA[2 * kb + 1], c1v);
                }
                accv = c0v + c1v;
            } else {
                const unsigned short* hl1 = hsh1 + colL * HPAD + koff;
                floatx4 a0c = {bias1, bias1, bias1, bias1};
                floatx4 a1c = {0, 0, 0, 0}, b0c = {0, 0, 0, 0}, b1c = {0, 0, 0, 0};
#pragma unroll
                for (int kb = 0; kb < 8; ++kb) {
                    a0c = mfma16(ld8(hl0 + (2 * kb) * 32),     wA[2 * kb],     a0c);
                    a1c = mfma16(ld8(hl0 + (2 * kb + 1) * 32), wA[2 * kb + 1], a1c);
                    b0c = mfma16(ld8(hl1 + (2 * kb) * 32),     wB[2 * kb],     b0c);
                    b1c = mfma16(ld8(hl1 + (2 * kb + 1) * 32), wB[2 * kb + 1], b1c);
                }
                accv = (a0c + a1c) + (b0c + b1c);
            }
            gbuf[half][wv][q * 4 + 0][colL] = accv[0];
            gbuf[half][wv][q * 4 + 1][colL] = accv[1];
            gbuf[half][wv][q * 4 + 2][colL] = accv[2];
            gbuf[half][wv][q * 4 + 3][colL] = accv[3];
        }
        asm volatile("s_waitcnt lgkmcnt(0)" ::: "memory");
        asm volatile("s_barrier" ::: "memory");
        // ---- elementwise + h stores ----
        if (act) {
            float gi = gbuf[half][0][eb][eu], gf = gbuf[half][1][eb][eu];
            float gg = gbuf[half][2][eb][eu], go = gbuf[half][3][eb][eu];
            float c2 = sigm(gf) * c + sigm(gi) * tanh_f(gg);
            float h2 = sigm(go) * tanh_f(c2);
            c = c2;
            unsigned hb = (unsigned)f2bf(h2);
            unsigned up = __shfl_down(hb, 1, 64);
            if ((eu & 1) == 0) {
                unsigned packed = hb | (up << 16);
                if (half == 0) {
                    __hip_atomic_store(
                        (unsigned*)(h0buf + (t & 1) * 8192 + eb * 512 + u0 + eu),
                        packed, __ATOMIC_RELAXED, __HIP_MEMORY_SCOPE_AGENT);
                } else {
                    int s = t - 1;
                    __hip_atomic_store(
                        (unsigned*)(h1buf + (s & 1) * 8192 + eb * 512 + u0 + eu),
                        packed, __ATOMIC_RELAXED, __HIP_MEMORY_SCOPE_AGENT);
                    asm volatile("" ::: "memory");   // keep h1-store oldest
                    *(unsigned*)&Hall[(size_t)(s * 16 + eb) * 512 + u0 + eu] = packed;
                    *(unsigned*)&Gmat[(size_t)(eb * 128 + s) * KFC + u0 + eu] = packed;
                }
            }
        }
        if (t < TSEQ) {
            asm volatile("" ::: "memory");   // order: h-store before prefetch
            if (half == 0) {
                if (t + 1 < TSEQ) {
                    a0raw = *(const ull*)(A0T + ((size_t)(t + 1) * GDIM + n0 + colL) * 16 + q * 4);
                    // [h-store, a0-load] outstanding -> oldest (h-store) acked
                    asm volatile("s_waitcnt vmcnt(1)" ::: "memory");
                } else {
                    asm volatile("s_waitcnt vmcnt(0)" ::: "memory");
                }
            } else {
                // [h1-store, Hall, Gmat] outstanding -> oldest (h1) acked
                asm volatile("s_waitcnt vmcnt(2)" ::: "memory");
            }
            asm volatile("s_barrier" ::: "memory");
            if (tid == 0)
                __hip_atomic_store(flags + wg * 32, t + 1,
                                   __ATOMIC_RELAXED, __HIP_MEMORY_SCOPE_AGENT);
            if (tid < 32) {
                int g = 0;
                while (__hip_atomic_load(flags + tid * 32, __ATOMIC_RELAXED,
                                         __HIP_MEMORY_SCOPE_AGENT) < t + 1) {
                    __builtin_amdgcn_s_sleep(1);
                    if (++g > (1 << 22)) break;   // fail loud, not hung
                }
            }
            asm volatile("s_barrier" ::: "memory");
        }
    }
}

// 4. ph = Hall @ Wh^T ; pe = enc @ We^T + attn_b   (z selects)
__global__ void phpe_kernel(const unsigned short* Hall, const unsigned short* encb,
                            const unsigned short* whb, const unsigned short* web,
                            const float* attnb, float* ph, float* pe) {
    bool ispe = (blockIdx.z != 0);
    const unsigned short* A  = ispe ? encb : Hall;
    const unsigned short* Bw = ispe ? web  : whb;
    float* out = ispe ? pe : ph;
    floatx4 acc[4] = {{0,0,0,0},{0,0,0,0},{0,0,0,0},{0,0,0,0}};
    int m0 = blockIdx.x * 64, n0 = blockIdx.y * 64;
    gemm64_acc(A, Bw, m0, n0, 512, 512, 16, acc);
    int tid = threadIdx.x, wv = tid >> 6, ln = tid & 63, colL = ln & 15, q = ln >> 4;
    int mrow = m0 + wv * 16;
#pragma unroll
    for (int nt = 0; nt < 4; ++nt) {
        int col = n0 + nt * 16 + colL;
        float bb = ispe ? attnb[col] : 0.f;
#pragma unroll
        for (int r = 0; r < 4; ++r)
            out[(size_t)(mrow + q * 4 + r) * 512 + col] = acc[nt][r] + bb;
    }
}

// 5. logits[t][l][b] = sum_k v_w[k] * tanh(ph[t*16+b][k] + pe[b*128+l][k])
__global__ void logits_kernel(const float* ph, const float* pe, const float* vw,
                              float* logits) {
    int m = blockIdx.x;             // t*16+b
    int t = m >> 4, b = m & 15;
    int tid = threadIdx.x, wv = tid >> 6, ln = tid & 63;
    const float* phr = ph + (size_t)m * 512 + ln * 8;
    floatx4 ph0 = *(const floatx4*)phr;
    floatx4 ph1 = *(const floatx4*)(phr + 4);
    const float* vwr = vw + ln * 8;
    floatx4 vw0 = *(const floatx4*)vwr;
    floatx4 vw1 = *(const floatx4*)(vwr + 4);
    for (int li = 0; li < 32; ++li) {
        int ll = wv * 32 + li;
        const float* per = pe + (size_t)(b * 128 + ll) * 512 + ln * 8;
        floatx4 p0 = *(const floatx4*)per;
        floatx4 p1 = *(const floatx4*)(per + 4);
        float s = 0.f;
#pragma unroll
        for (int j = 0; j < 4; ++j) s += vw0[j] * tanh_f(ph0[j] + p0[j]);
#pragma unroll
        for (int j = 0; j < 4; ++j) s += vw1[j] * tanh_f(ph1[j] + p1[j]);
#pragma unroll
        for (int off = 32; off; off >>= 1) s += __shfl_xor(s, off, 64);
        if (ln == 0) logits[((size_t)t * 128 + ll) * 16 + b] = s;
    }
}

// 6. softmax over b (axis=1 of (T,B,L)) -> att_bf16[b][t][l]
__global__ void att_kernel(const float* logits, unsigned short* attb) {
    int t = blockIdx.x, l = threadIdx.x;     // 128 threads
    const float* p = logits + ((size_t)t * 128 + l) * 16;
    float x[16], mx = -1e30f;
#pragma unroll
    for (int j = 0; j < 16; ++j) { x[j] = p[j]; mx = fmaxf(mx, x[j]); }
    float s = 0.f;
#pragma unroll
    for (int j = 0; j < 16; ++j) { x[j] = __expf(x[j] - mx); s += x[j]; }
    float inv = __builtin_amdgcn_rcpf(s);
#pragma unroll
    for (int j = 0; j < 16; ++j)
        attb[((size_t)j * 128 + t) * 128 + l] = f2bf(x[j] * inv);
}

// 7. weighted[b][t][h] = att[b] @ enc[b]  ->  G[b*128+t][512+h]
__global__ void weighted_kernel(const unsigned short* attb, const unsigned short* enctb,
                                unsigned short* Gmat) {
    int b = blockIdx.z;
    floatx4 acc[4] = {{0,0,0,0},{0,0,0,0},{0,0,0,0},{0,0,0,0}};
    int m0 = blockIdx.x * 64, n0 = blockIdx.y * 64;
    gemm64_acc(attb + (size_t)b * 128 * 128, enctb + (size_t)b * 512 * 128,
               m0, n0, 128, 128, 4, acc);
    int tid = threadIdx.x, wv = tid >> 6, ln = tid & 63, colL = ln & 15, q = ln >> 4;
    int mrow = m0 + wv * 16;
#pragma unroll
    for (int nt = 0; nt < 4; ++nt) {
        int col = n0 + nt * 16 + colL;
#pragma unroll
        for (int r = 0; r < 4; ++r)
            Gmat[(size_t)(b * 128 + mrow + q * 4 + r) * KFC + 512 + col] = f2bf(acc[nt][r]);
    }
}

// ============================================================================
// 8. fc GEMM (m97-structure) + fused per-row (max, sumexp) partials.
// ============================================================================
__global__ __launch_bounds__(256)
void fc_kernel(const unsigned short* G, const unsigned short* fcWb,
               const float* fcb, float2* partials) {
    __shared__ __align__(16) unsigned short lA[128 * 64];
    __shared__ __align__(16) unsigned short lB[128 * 64];
    __shared__ float2 pbuf[128][2];
    int nwg = blockIdx.x;            // 0..249
    int mwg = blockIdx.y;            // 0..15
    int n_base = nwg * 128, m_base = mwg * 128;
    int tid = threadIdx.x, wv = tid >> 6, l = tid & 63;
    int wr = wv >> 1, wc = wv & 1;
    int colL = l & 15, q16 = l >> 4, koff = q16 * 8;
    int srow = l >> 3, scol = (l & 7) * 8;     // staging sub-pattern per chunk

    floatx4 acc[4][4];
#pragma unroll
    for (int i = 0; i < 4; ++i)
#pragma unroll
        for (int j = 0; j < 4; ++j) acc[i][j] = (floatx4){0, 0, 0, 0};

    const unsigned short* gA = G    + (size_t)m_base * KFC;
    const unsigned short* gB = fcWb + (size_t)n_base * KFC;

    for (int kt = 0; kt < 16; ++kt) {
        if (kt) __syncthreads();     // previous tile's reads done before overwrite
        int k0 = kt * 64;
#pragma unroll
        for (int j = 0; j < 4; ++j) {
            int c = wv * 4 + j;
            const unsigned short* ga = gA + (size_t)(c * 8 + srow) * KFC + k0 + scol;
            const unsigned short* gb = gB + (size_t)(c * 8 + srow) * KFC + k0 + scol;
            GLD16(ga, lA + c * 512);
            GLD16(gb, lB + c * 512);
        }
        __syncthreads();             // barrier drains vmcnt -> tiles resident
#pragma unroll
        for (int ks = 0; ks < 2; ++ks) {
            const unsigned short* ap = lA + (wr * 64 + colL) * 64 + ks * 32 + koff;
            const unsigned short* bp = lB + (wc * 64 + colL) * 64 + ks * 32 + koff;
            short8 aF[4], bF[4];
#pragma unroll
            for (int ma = 0; ma < 4; ++ma) aF[ma] = ld8(ap + ma * 16 * 64);
#pragma unroll
            for (int nb = 0; nb < 4; ++nb) bF[nb] = ld8(bp + nb * 16 * 64);
#pragma unroll
            for (int ma = 0; ma < 4; ++ma)
#pragma unroll
                for (int nb = 0; nb < 4; ++nb)
                    acc[ma][nb] = mfma16(aF[ma], bF[nb], acc[ma][nb]);
        }
    }

    // ---- epilogue: per-row (max, sumexp) over this WG's 128 cols ----
    float cb[4];
#pragma unroll
    for (int nb = 0; nb < 4; ++nb)
        cb[nb] = fcb[n_base + wc * 64 + nb * 16 + colL];

#pragma unroll
    for (int ma = 0; ma < 4; ++ma) {
#pragma unroll
        for (int r = 0; r < 4; ++r) {
            float v0 = acc[ma][0][r] + cb[0];
            float v1 = acc[ma][1][r] + cb[1];
            float v2 = acc[ma][2][r] + cb[2];
            float v3 = acc[ma][3][r] + cb[3];
            float M = fmaxf(fmaxf(v0, v1), fmaxf(v2, v3));
#pragma unroll
            for (int off = 1; off < 16; off <<= 1) M = fmaxf(M, __shfl_xor(M, off, 64));
            float e = __expf(v0 - M) + __expf(v1 - M) + __expf(v2 - M) + __expf(v3 - M);
#pragma unroll
            for (int off = 1; off < 16; off <<= 1) e += __shfl_xor(e, off, 64);
            if (colL == 0)
                pbuf[wr * 64 + ma * 16 + q16 * 4 + r][wc] = make_float2(M, e);
        }
    }
    __syncthreads();
    if (tid < 128) {    // merge the two col-halves, write global partial
        float2 a = pbuf[tid][0], b = pbuf[tid][1];
        float M = fmaxf(a.x, b.x);
        float S = a.y * __expf(a.x - M) + b.y * __expf(b.x - M);
        partials[(size_t)(m_base + tid) * 250 + nwg] = make_float2(M, S);
    }
}

// 9. target logit per row: z_y = G[r] . fc_W[y] + fc_b[y]
__global__ void tgt_kernel(const unsigned short* G, const float* fcW, const float* fcb,
                           const int* X, float* tgt) {
    int r = blockIdx.x * 4 + (threadIdx.x >> 6);
    int ln = threadIdx.x & 63;
    int b = r >> 7, t = r & 127;
    int y = X[b * 129 + t + 1];
    y = (y < 0) ? 0 : ((y >= VOCAB) ? VOCAB - 1 : y);   // defensive
    const unsigned short* g = G + (size_t)r * KFC;
    const float* w = fcW + (size_t)y * KFC;
    float s = 0.f;
    for (int j = ln; j < KFC; j += 64) s += bf2f(g[j]) * w[j];
#pragma unroll
    for (int off = 32; off; off >>= 1) s += __shfl_xor(s, off, 64);
    if (ln == 0) tgt[r] = s + fcb[y];
}

// 10. merge partials -> logsumexp -> masked mean NLL
__global__ void finalize_kernel(const float2* partials, const float* tgt,
                                const int* X, float* out) {
    int tid = threadIdx.x;
    float vs = 0.f, vc = 0.f;
    for (int r = tid; r < NROW; r += 256) {
        const float2* p = partials + (size_t)r * 250;
        float M = p[0].x, S = p[0].y;
        for (int i = 1; i < 250; ++i) {
            float2 qq = p[i];
            float nm = fmaxf(M, qq.x);
            S = S * __expf(M - nm) + qq.y * __expf(qq.x - nm);
            M = nm;
        }
        float lse = M + __logf(S);
        int b = r >> 7, t = r & 127;
        int y = X[b * 129 + t + 1];
        if (y != 0) { vs += lse - tgt[r]; vc += 1.f; }
    }
    __shared__ float sv[256], sc[256];
    sv[tid] = vs; sc[tid] = vc;
    __syncthreads();
    for (int s = 128; s; s >>= 1) {
        if (tid < s) { sv[tid] += sv[tid + s]; sc[tid] += sc[tid + s]; }
        __syncthreads();
    }
    if (tid == 0) out[0] = sv[0] / sc[0];
}

// ============================================================================
// launcher
// ============================================================================
extern "C" void kernel_launch(void* const* d_in, const int* in_sizes, int n_in,
                              void* d_out, int out_size, void* d_ws, size_t ws_size,
                              hipStream_t stream) {
    const int*   X     = (const int*)d_in[0];
    const float* enc   = (const float*)d_in[2];
    const float* emb   = (const float*)d_in[3];
    const float* Wih0  = (const float*)d_in[4];
    const float* Whh0  = (const float*)d_in[5];
    const float* bih0  = (const float*)d_in[6];
    const float* bhh0  = (const float*)d_in[7];
    const float* Wih1  = (const float*)d_in[8];
    const float* Whh1  = (const float*)d_in[9];
    const float* bih1  = (const float*)d_in[10];
    const float* bhh1  = (const float*)d_in[11];
    const float* attnW = (const float*)d_in[12];
    const float* attnb = (const float*)d_in[13];
    const float* vw    = (const float*)d_in[14];
    const float* fcW   = (const float*)d_in[15];
    const float* fcb   = (const float*)d_in[16];
    const float* h0    = (const float*)d_in[17];
    const float* c0    = (const float*)d_in[18];

    char* ws = (char*)d_ws;
    size_t off = 0;
    auto take = [&](size_t bytes) { char* p = ws + off; off += (bytes + 255) & ~(size_t)255; return p; };
    int*            ctrl    = (int*)           take(12288);
    unsigned short* wih0b   = (unsigned short*)take(2097152);
    unsigned short* whh0b   = (unsigned short*)take(2097152);
    unsigned short* wih1b   = (unsigned short*)take(2097152);
    unsigned short* whh1b   = (unsigned short*)take(2097152);
    unsigned short* whb     = (unsigned short*)take(524288);
    unsigned short* web     = (unsigned short*)take(524288);
    unsigned short* encb    = (unsigned short*)take(2097152);
    unsigned short* enctb   = (unsigned short*)take(2097152);
    unsigned short* xsb     = (unsigned short*)take(2097152);
    unsigned short* h0buf   = (unsigned short*)take(32768);
    unsigned short* h1buf   = (unsigned short*)take(32768);
    unsigned short* A0b     = (unsigned short*)take(8388608);
    unsigned short* hallb   = (unsigned short*)take(2097152);
    unsigned short* gmat    = (unsigned short*)take(4194304);
    float*          ph      = (float*)         take(4194304);
    float*          pe      = (float*)         take(4194304);
    float*          logitsb = (float*)         take(1048576);
    unsigned short* attb    = (unsigned short*)take(524288);
    float2*         parts   = (float2*)        take(4096000);
    float*          tgt     = (float*)         take(8192);
    unsigned short* fcWb    = (unsigned short*)take(65536000);
    size_t need = off;
    (void)in_sizes; (void)n_in;

    if (ws_size < need) {
        // Not enough scratch: fail visibly (absmax error) instead of faulting.
        hipLaunchKernelGGL(zero_out_kernel, dim3((out_size + 63) / 64), dim3(64),
                           0, stream, (float*)d_out, out_size);
        return;
    }

    hipLaunchKernelGGL(prep_kernel, dim3(62784), dim3(256), 0, stream,
                       X, enc, emb, Wih0, Whh0, Wih1, Whh1, attnW, h0, fcW,
                       wih0b, whh0b, wih1b, whh1b, whb, web, encb, enctb,
                       xsb, h0buf, h1buf, fcWb, ctrl);
    hipLaunchKernelGGL(a0_kernel, dim3(32, 32), dim3(256), 0, stream,
                       xsb, wih0b, bih0, bhh0, A0b);
    hipLaunchKernelGGL(lstm_kernel, dim3(32), dim3(512), 0, stream,
                       A0b, whh0b, wih1b, whh1b, bih1, bhh1, c0,
                       h0buf, h1buf, hallb, gmat, ctrl);
    hipLaunchKernelGGL(phpe_kernel, dim3(32, 8, 2), dim3(256), 0, stream,
                       hallb, encb, whb, web, attnb, ph, pe);
    hipLaunchKernelGGL(logits_kernel, dim3(2048), dim3(256), 0, stream,
                       ph, pe, vw, logitsb);
    hipLaunchKernelGGL(att_kernel, dim3(128), dim3(128), 0, stream,
                       logitsb, attb);
    hipLaunchKernelGGL(weighted_kernel, dim3(2, 8, 16), dim3(256), 0, stream,
                       attb, enctb, gmat);
    hipLaunchKernelGGL(fc_kernel, dim3(250, 16), dim3(256), 0, stream,
                       gmat, fcWb, fcb, parts);
    hipLaunchKernelGGL(tgt_kernel, dim3(512), dim3(256), 0, stream,
                       gmat, fcW, fcb, X, tgt);
    hipLaunchKernelGGL(finalize_kernel, dim3(1), dim3(256), 0, stream,
                       parts, tgt, X, (float*)d_out);
}

// Round 5
// 1813.852 us; speedup vs baseline: 1.0330x; 1.0330x over previous
//
#include <hip/hip_runtime.h>

// ============================================================================
// DecoderGenerator: 2-layer LSTM decoder + additive attention + big vocab
// projection + NLL, fully fused on-device.
//
//   1. prep_kernel     : bf16-cast weights/enc/fcW, gather embeddings,
//                        transpose enc, init h-state buffers, zero flags.
//   2. a0_kernel       : A0T[t][col][b] = xs @ W_ih0^T + b  (transposed store)
//   3. lstm_kernel     : persistent 32-WG x 512-thread kernel, 129 ticks.
//                        ROUND 10: revert to the measured-best ROUND-1 sync
//                        structure (__syncthreads barriers, publish after
//                        full drain, prefetch after publish). Keep the
//                        counter-proven traffic wins from round 3: A0T
//                        coalesced prefetch, interleaved lane-consecutive
//                        staging, HPAD=516, split MFMA chains.
//   4. phpe_kernel     : ph = Hall@Wh^T ; pe = enc@We^T + attn_b
//   5. logits_kernel   : logits[t,b,l] = sum_k v_w[k] tanh(ph+pe)
//   6. att_kernel      : softmax over b (axis=1 of (T,B,L) — per reference!)
//   7. weighted_kernel : weighted = att @ enc  (per-batch GEMM) -> G[:,512:]
//   8. fc_kernel       : m97-structure 128x128xBK64 tiled GEMM + fused
//                        per-row (max,sumexp) partials.
//   9. tgt_kernel      : target logits z_y per row
//  10. finalize_kernel : logsumexp merge + masked-mean NLL -> d_out[0]
// ============================================================================

#define DI __device__ __forceinline__

typedef __attribute__((ext_vector_type(8))) short short8;
typedef __attribute__((ext_vector_type(4))) float floatx4;
typedef unsigned long long ull;

#define TSEQ   128
#define VOCAB  32000
#define GDIM   2048   // 4*H
#define NROW   2048   // B*T
#define KFC    1024   // 2*H
#define HPAD   516    // LDS row stride (ushorts): 516*2/4 = 258 ≡ 2 (mod 32)

// ---------------- small helpers ----------------
DI float bf2f(unsigned short u) {
    union { unsigned u; float f; } x; x.u = ((unsigned)u) << 16; return x.f;
}
DI unsigned short f2bf(float f) {   // RNE float -> bf16
    unsigned u = __float_as_uint(f);
    unsigned r = (u + 0x7FFF + ((u >> 16) & 1)) >> 16;
    return (unsigned short)r;
}
DI short8 ld8(const unsigned short* p) { return *(const short8*)p; }
DI floatx4 mfma16(short8 a, short8 b, floatx4 c) {
    return __builtin_amdgcn_mfma_f32_16x16x32_bf16(a, b, c, 0, 0, 0);
}
DI float sigm(float x) { return __builtin_amdgcn_rcpf(1.f + __expf(-x)); }
DI float tanh_f(float x) {
    float xc = fminf(8.f, fmaxf(-8.f, x));
    float e  = __expf(2.f * xc);
    return (e - 1.f) * __builtin_amdgcn_rcpf(e + 1.f);
}

// async global -> LDS, 16B per lane. LDS dest must be wave-uniform base;
// lane l writes base + l*16. Global src is per-lane.
#define GLD16(gsrc, ldst)                                                     \
    __builtin_amdgcn_global_load_lds(                                         \
        (const __attribute__((address_space(1))) unsigned int*)(gsrc),        \
        (__attribute__((address_space(3))) unsigned int*)(ldst), 16, 0, 0)

// fallback path: make the failure visible instead of faulting
__global__ void zero_out_kernel(float* out, int n) {
    int i = blockIdx.x * 64 + threadIdx.x;
    if (i < n) out[i] = 0.f;
}

// ============================================================================
// 1. prep kernel : segmented grid-stride over all conversion jobs
// ============================================================================
__global__ void prep_kernel(const int* X, const float* enc, const float* emb,
                            const float* Wih0, const float* Whh0,
                            const float* Wih1, const float* Whh1,
                            const float* attnW, const float* h0,
                            const float* fcW,
                            unsigned short* wih0b, unsigned short* whh0b,
                            unsigned short* wih1b, unsigned short* whh1b,
                            unsigned short* whb, unsigned short* web,
                            unsigned short* encb, unsigned short* enctb,
                            unsigned short* xsb,
                            unsigned short* h0buf, unsigned short* h1buf,
                            unsigned short* fcWb,
                            int* ctrl) {
    if (blockIdx.x == 0) {              // zero all 3072 flag ints
#pragma unroll
        for (int j = 0; j < 12; ++j) ctrl[threadIdx.x + 256 * j] = 0;
    }
    long i = (long)blockIdx.x * 256 + threadIdx.x;
    const long NW = 1048576;
    const long NA = 262144;            // 512x512 half of attn_W
    if (i < NW) { wih0b[i] = f2bf(Wih0[i]); return; } i -= NW;
    if (i < NW) { whh0b[i] = f2bf(Whh0[i]); return; } i -= NW;
    if (i < NW) { wih1b[i] = f2bf(Wih1[i]); return; } i -= NW;
    if (i < NW) { whh1b[i] = f2bf(Whh1[i]); return; } i -= NW;
    if (i < NA) { long k = i >> 9, h = i & 511; whb[i] = f2bf(attnW[k * 1024 + h]);       return; } i -= NA;
    if (i < NA) { long k = i >> 9, h = i & 511; web[i] = f2bf(attnW[k * 1024 + 512 + h]); return; } i -= NA;
    if (i < NW) { encb[i] = f2bf(enc[i]); return; } i -= NW;
    if (i < NW) {  // enc_t[b][h][l] = enc[b][l][h]
        long b = i >> 16, r = i & 65535, h = r >> 7, l = r & 127;
        enctb[i] = f2bf(enc[(b * 128 + l) * 512 + h]); return;
    } i -= NW;
    if (i < NW) {  // xs[t*16+b][e] = emb[X[b][t]][e]
        long m = i >> 9, e = i & 511, t = m >> 4, b = m & 15;
        int xi = X[b * 129 + t];
        xi = (xi < 0) ? 0 : ((xi >= VOCAB) ? VOCAB - 1 : xi);   // defensive
        xsb[i] = f2bf(emb[(long)xi * 512 + e]); return;
    } i -= NW;
    if (i < 16384) {  // h inits into parity-1 buffers
        long layer = i >> 13, r = i & 8191;
        unsigned short v = f2bf(h0[layer * 8192 + r]);
        if (layer == 0) h0buf[8192 + r] = v; else h1buf[8192 + r] = v;
        return;
    } i -= 16384;
    if (i < 8192000) {  // fcW f32 -> bf16, 4 elements per thread
        float4 v = ((const float4*)fcW)[i];
        ushort4 o;
        o.x = f2bf(v.x); o.y = f2bf(v.y); o.z = f2bf(v.z); o.w = f2bf(v.w);
        ((ushort4*)fcWb)[i] = o;
    }
}

// ============================================================================
// shared 64x64 MFMA tile: C[m0..+63][n0..+63] += A(m,k) * B(n,k)^T
// ============================================================================
DI void gemm64_acc(const unsigned short* A, const unsigned short* Bw,
                   int m0, int n0, int lda, int ldb, int nkb, floatx4 acc[4]) {
    int tid = threadIdx.x;
    int wv = tid >> 6, ln = tid & 63;
    int colL = ln & 15, koff = (ln >> 4) * 8;
    const unsigned short* ar  = A  + (size_t)(m0 + wv * 16 + colL) * lda + koff;
    const unsigned short* br0 = Bw + (size_t)(n0 +  0 + colL) * ldb + koff;
    const unsigned short* br1 = Bw + (size_t)(n0 + 16 + colL) * ldb + koff;
    const unsigned short* br2 = Bw + (size_t)(n0 + 32 + colL) * ldb + koff;
    const unsigned short* br3 = Bw + (size_t)(n0 + 48 + colL) * ldb + koff;
    for (int kb = 0; kb < nkb; ++kb) {
        short8 af = ld8(ar + kb * 32);
        acc[0] = mfma16(af, ld8(br0 + kb * 32), acc[0]);
        acc[1] = mfma16(af, ld8(br1 + kb * 32), acc[1]);
        acc[2] = mfma16(af, ld8(br2 + kb * 32), acc[2]);
        acc[3] = mfma16(af, ld8(br3 + kb * 32), acc[3]);
    }
}

// 2. A0T[(t*GDIM + col)*16 + b] = (xs @ W_ih0^T)[t*16+b][col] + bias
//    (transposed so the lstm prefetch is one coalesced 8B load per lane)
__global__ void a0_kernel(const unsigned short* xs, const unsigned short* wih0b,
                          const float* bih0, const float* bhh0, unsigned short* A0T) {
    floatx4 acc[4] = {{0,0,0,0},{0,0,0,0},{0,0,0,0},{0,0,0,0}};
    int m0 = blockIdx.x * 64, n0 = blockIdx.y * 64;
    gemm64_acc(xs, wih0b, m0, n0, 512, 512, 16, acc);
    int tid = threadIdx.x, wv = tid >> 6, ln = tid & 63, colL = ln & 15, q = ln >> 4;
    int trow = (m0 >> 4) + wv;           // rows mrow..mrow+15 = one t
#pragma unroll
    for (int nt = 0; nt < 4; ++nt) {
        int col = n0 + nt * 16 + colL;
        float bb = bih0[col] + bhh0[col];
#pragma unroll
        for (int r = 0; r < 4; ++r)
            A0T[((size_t)trow * GDIM + col) * 16 + q * 4 + r] = f2bf(acc[nt][r] + bb);
    }
}

// ============================================================================
// 3. persistent LSTM kernel.  32 WGs x 512 threads.  ROUND 10.
//    ROUND-1 sync structure (measured best: 455us):
//      stage -> __syncthreads -> MFMA/gbuf -> __syncthreads -> elementwise +
//      h-stores -> __syncthreads (full drain) -> flag publish -> A0 prefetch
//      -> poll -> __syncthreads
//    + traffic wins: A0T 8B coalesced prefetch, interleaved staging,
//      HPAD=516, split MFMA chains.
// ============================================================================
__global__ __launch_bounds__(512, 1)
void lstm_kernel(const unsigned short* A0T,
                 const unsigned short* whh0b, const unsigned short* wih1b,
                 const unsigned short* whh1b,
                 const float* bih1, const float* bhh1, const float* c0in,
                 unsigned short* h0buf, unsigned short* h1buf,
                 unsigned short* Hall, unsigned short* Gmat, int* flags) {
    __shared__ unsigned short hsh0[16 * HPAD];   // h0[t-1], shared by both halves
    __shared__ unsigned short hsh1[16 * HPAD];   // h1[t-2], read by L1 half
    __shared__ float gbuf[2][4][16][17];         // [half][gate][batch][unit]
    int wg = blockIdx.x;            // 0..31
    int tid = threadIdx.x;          // 0..511
    int half = tid >> 8;            // 0 = L0, 1 = L1
    int lt   = tid & 255;
    int wv = lt >> 6, ln = lt & 63;
    int u0 = wg * 16;
    int n0 = wv * 512 + u0;         // gate column base (wave-of-half = gate)
    int colL = ln & 15, q = ln >> 4, koff = q * 8;
    int eb = lt >> 4, eu = lt & 15; // elementwise mapping within half
    float c = c0in[half * 8192 + eb * 512 + u0 + eu];
    float bias1 = (half == 1) ? (bih1[n0 + colL] + bhh1[n0 + colL]) : 0.f;

    // ---- one-time: weight slices into registers ----
    short8 wA[16], wB[16];
    if (half == 0) {
        const unsigned short* wr0 = whh0b + (size_t)(n0 + colL) * 512 + koff;
#pragma unroll
        for (int kb = 0; kb < 16; ++kb) wA[kb] = ld8(wr0 + kb * 32);
#pragma unroll
        for (int kb = 0; kb < 16; ++kb) wB[kb] = wA[kb];   // unused, keep defined
    } else {
        const unsigned short* wr1 = wih1b + (size_t)(n0 + colL) * 512 + koff;
        const unsigned short* wr2 = whh1b + (size_t)(n0 + colL) * 512 + koff;
#pragma unroll
        for (int kb = 0; kb < 16; ++kb) wA[kb] = ld8(wr1 + kb * 32);
#pragma unroll
        for (int kb = 0; kb < 16; ++kb) wB[kb] = ld8(wr2 + kb * 32);
    }

    // A0 prefetch for tick 0 (L0 half): one coalesced 8B load
    ull a0raw = 0;
    if (half == 0)
        a0raw = *(const ull*)(A0T + ((size_t)0 * GDIM + n0 + colL) * 16 + q * 4);

#pragma unroll 1
    for (int t = 0; t <= TSEQ; ++t) {
        bool actL1 = (t >= 1);
        bool act = half ? actL1 : (t < TSEQ);
        // ---- stage h vectors LLC -> LDS (interleaved 8B, conflict-free) ----
        {
            const ull* s0 = (const ull*)(h0buf + ((t - 1) & 1) * 8192);
            ull v0[4];
#pragma unroll
            for (int k = 0; k < 4; ++k)
                v0[k] = __hip_atomic_load(s0 + tid + 512 * k, __ATOMIC_RELAXED,
                                          __HIP_MEMORY_SCOPE_AGENT);
            ull v1[4];
            if (actL1) {
                const ull* s1 = (const ull*)(h1buf + ((t - 2) & 1) * 8192);
#pragma unroll
                for (int k = 0; k < 4; ++k)
                    v1[k] = __hip_atomic_load(s1 + tid + 512 * k, __ATOMIC_RELAXED,
                                              __HIP_MEMORY_SCOPE_AGENT);
            }
#pragma unroll
            for (int k = 0; k < 4; ++k) {
                int u = tid + 512 * k;
                *(ull*)&hsh0[(u >> 7) * HPAD + (u & 127) * 4] = v0[k];
            }
            if (actL1) {
#pragma unroll
                for (int k = 0; k < 4; ++k) {
                    int u = tid + 512 * k;
                    *(ull*)&hsh1[(u >> 7) * HPAD + (u & 127) * 4] = v1[k];
                }
            }
        }
        __syncthreads();
        // ---- MFMA: LDS fragments x register weights (split chains) ----
        if (act) {
            floatx4 accv;
            const unsigned short* hl0 = hsh0 + colL * HPAD + koff;
            if (half == 0) {
                floatx4 c0v, c1v = {0, 0, 0, 0};
                c0v[0] = bf2f((unsigned short)(a0raw));
                c0v[1] = bf2f((unsigned short)(a0raw >> 16));
                c0v[2] = bf2f((unsigned short)(a0raw >> 32));
                c0v[3] = bf2f((unsigned short)(a0raw >> 48));
#pragma unroll
                for (int kb = 0; kb < 8; ++kb) {
                    c0v = mfma16(ld8(hl0 + (2 * kb) * 32),     wA[2 * kb],     c0v);
                    c1v = mfma16(ld8(hl0 + (2 * kb + 1) * 32), wA[2 * kb + 1], c1v);
                }
                accv = c0v + c1v;
            } else {
                const unsigned short* hl1 = hsh1 + colL * HPAD + koff;
                floatx4 a0c = {bias1, bias1, bias1, bias1};
                floatx4 a1c = {0, 0, 0, 0}, b0c = {0, 0, 0, 0}, b1c = {0, 0, 0, 0};
#pragma unroll
                for (int kb = 0; kb < 8; ++kb) {
                    a0c = mfma16(ld8(hl0 + (2 * kb) * 32),     wA[2 * kb],     a0c);
                    a1c = mfma16(ld8(hl0 + (2 * kb + 1) * 32), wA[2 * kb + 1], a1c);
                    b0c = mfma16(ld8(hl1 + (2 * kb) * 32),     wB[2 * kb],     b0c);
                    b1c = mfma16(ld8(hl1 + (2 * kb + 1) * 32), wB[2 * kb + 1], b1c);
                }
                accv = (a0c + a1c) + (b0c + b1c);
            }
            gbuf[half][wv][q * 4 + 0][colL] = accv[0];
            gbuf[half][wv][q * 4 + 1][colL] = accv[1];
            gbuf[half][wv][q * 4 + 2][colL] = accv[2];
            gbuf[half][wv][q * 4 + 3][colL] = accv[3];
        }
        __syncthreads();
        // ---- elementwise + h stores ----
        if (act) {
            float gi = gbuf[half][0][eb][eu], gf = gbuf[half][1][eb][eu];
            float gg = gbuf[half][2][eb][eu], go = gbuf[half][3][eb][eu];
            float c2 = sigm(gf) * c + sigm(gi) * tanh_f(gg);
            float h2 = sigm(go) * tanh_f(c2);
            c = c2;
            unsigned hb = (unsigned)f2bf(h2);
            unsigned up = __shfl_down(hb, 1, 64);
            if ((eu & 1) == 0) {
                unsigned packed = hb | (up << 16);
                if (half == 0) {
                    __hip_atomic_store(
                        (unsigned*)(h0buf + (t & 1) * 8192 + eb * 512 + u0 + eu),
                        packed, __ATOMIC_RELAXED, __HIP_MEMORY_SCOPE_AGENT);
                } else {
                    int s = t - 1;
                    __hip_atomic_store(
                        (unsigned*)(h1buf + (s & 1) * 8192 + eb * 512 + u0 + eu),
                        packed, __ATOMIC_RELAXED, __HIP_MEMORY_SCOPE_AGENT);
                    *(unsigned*)&Hall[(size_t)(s * 16 + eb) * 512 + u0 + eu] = packed;
                    *(unsigned*)&Gmat[(size_t)(eb * 128 + s) * KFC + u0 + eu] = packed;
                }
            }
        }
        if (t < TSEQ) {
            // publish: __syncthreads drains all waves' vmem (hipcc emits
            // s_waitcnt vmcnt(0) before s_barrier) -> h-stores LLC-visible.
            __syncthreads();
            if (tid == 0)
                __hip_atomic_store(flags + wg * 32, t + 1,
                                   __ATOMIC_RELAXED, __HIP_MEMORY_SCOPE_AGENT);
            // prefetch next tick's A0 now — overlaps the poll window
            if (half == 0 && t + 1 < TSEQ)
                a0raw = *(const ull*)(A0T + ((size_t)(t + 1) * GDIM + n0 + colL) * 16 + q * 4);
            // wait: relaxed polls (no cache maintenance per iteration)
            if (tid < 32) {
                int g = 0;
                while (__hip_atomic_load(flags + tid * 32, __ATOMIC_RELAXED,
                                         __HIP_MEMORY_SCOPE_AGENT) < t + 1) {
                    __builtin_amdgcn_s_sleep(1);
                    if (++g > (1 << 22)) break;   // fail loud, not hung
                }
            }
            __syncthreads();
        }
    }
}

// 4. ph = Hall @ Wh^T ; pe = enc @ We^T + attn_b   (z selects)
__global__ void phpe_kernel(const unsigned short* Hall, const unsigned short* encb,
                            const unsigned short* whb, const unsigned short* web,
                            const float* attnb, float* ph, float* pe) {
    bool ispe = (blockIdx.z != 0);
    const unsigned short* A  = ispe ? encb : Hall;
    const unsigned short* Bw = ispe ? web  : whb;
    float* out = ispe ? pe : ph;
    floatx4 acc[4] = {{0,0,0,0},{0,0,0,0},{0,0,0,0},{0,0,0,0}};
    int m0 = blockIdx.x * 64, n0 = blockIdx.y * 64;
    gemm64_acc(A, Bw, m0, n0, 512, 512, 16, acc);
    int tid = threadIdx.x, wv = tid >> 6, ln = tid & 63, colL = ln & 15, q = ln >> 4;
    int mrow = m0 + wv * 16;
#pragma unroll
    for (int nt = 0; nt < 4; ++nt) {
        int col = n0 + nt * 16 + colL;
        float bb = ispe ? attnb[col] : 0.f;
#pragma unroll
        for (int r = 0; r < 4; ++r)
            out[(size_t)(mrow + q * 4 + r) * 512 + col] = acc[nt][r] + bb;
    }
}

// 5. logits[t][l][b] = sum_k v_w[k] * tanh(ph[t*16+b][k] + pe[b*128+l][k])
__global__ void logits_kernel(const float* ph, const float* pe, const float* vw,
                              float* logits) {
    int m = blockIdx.x;             // t*16+b
    int t = m >> 4, b = m & 15;
    int tid = threadIdx.x, wv = tid >> 6, ln = tid & 63;
    const float* phr = ph + (size_t)m * 512 + ln * 8;
    floatx4 ph0 = *(const floatx4*)phr;
    floatx4 ph1 = *(const floatx4*)(phr + 4);
    const float* vwr = vw + ln * 8;
    floatx4 vw0 = *(const floatx4*)vwr;
    floatx4 vw1 = *(const floatx4*)(vwr + 4);
    for (int li = 0; li < 32; ++li) {
        int ll = wv * 32 + li;
        const float* per = pe + (size_t)(b * 128 + ll) * 512 + ln * 8;
        floatx4 p0 = *(const floatx4*)per;
        floatx4 p1 = *(const floatx4*)(per + 4);
        float s = 0.f;
#pragma unroll
        for (int j = 0; j < 4; ++j) s += vw0[j] * tanh_f(ph0[j] + p0[j]);
#pragma unroll
        for (int j = 0; j < 4; ++j) s += vw1[j] * tanh_f(ph1[j] + p1[j]);
#pragma unroll
        for (int off = 32; off; off >>= 1) s += __shfl_xor(s, off, 64);
        if (ln == 0) logits[((size_t)t * 128 + ll) * 16 + b] = s;
    }
}

// 6. softmax over b (axis=1 of (T,B,L)) -> att_bf16[b][t][l]
__global__ void att_kernel(const float* logits, unsigned short* attb) {
    int t = blockIdx.x, l = threadIdx.x;     // 128 threads
    const float* p = logits + ((size_t)t * 128 + l) * 16;
    float x[16], mx = -1e30f;
#pragma unroll
    for (int j = 0; j < 16; ++j) { x[j] = p[j]; mx = fmaxf(mx, x[j]); }
    float s = 0.f;
#pragma unroll
    for (int j = 0; j < 16; ++j) { x[j] = __expf(x[j] - mx); s += x[j]; }
    float inv = __builtin_amdgcn_rcpf(s);
#pragma unroll
    for (int j = 0; j < 16; ++j)
        attb[((size_t)j * 128 + t) * 128 + l] = f2bf(x[j] * inv);
}

// 7. weighted[b][t][h] = att[b] @ enc[b]  ->  G[b*128+t][512+h]
__global__ void weighted_kernel(const unsigned short* attb, const unsigned short* enctb,
                                unsigned short* Gmat) {
    int b = blockIdx.z;
    floatx4 acc[4] = {{0,0,0,0},{0,0,0,0},{0,0,0,0},{0,0,0,0}};
    int m0 = blockIdx.x * 64, n0 = blockIdx.y * 64;
    gemm64_acc(attb + (size_t)b * 128 * 128, enctb + (size_t)b * 512 * 128,
               m0, n0, 128, 128, 4, acc);
    int tid = threadIdx.x, wv = tid >> 6, ln = tid & 63, colL = ln & 15, q = ln >> 4;
    int mrow = m0 + wv * 16;
#pragma unroll
    for (int nt = 0; nt < 4; ++nt) {
        int col = n0 + nt * 16 + colL;
#pragma unroll
        for (int r = 0; r < 4; ++r)
            Gmat[(size_t)(b * 128 + mrow + q * 4 + r) * KFC + 512 + col] = f2bf(acc[nt][r]);
    }
}

// ============================================================================
// 8. fc GEMM (m97-structure) + fused per-row (max, sumexp) partials.
// ============================================================================
__global__ __launch_bounds__(256)
void fc_kernel(const unsigned short* G, const unsigned short* fcWb,
               const float* fcb, float2* partials) {
    __shared__ __align__(16) unsigned short lA[128 * 64];
    __shared__ __align__(16) unsigned short lB[128 * 64];
    __shared__ float2 pbuf[128][2];
    int nwg = blockIdx.x;            // 0..249
    int mwg = blockIdx.y;            // 0..15
    int n_base = nwg * 128, m_base = mwg * 128;
    int tid = threadIdx.x, wv = tid >> 6, l = tid & 63;
    int wr = wv >> 1, wc = wv & 1;
    int colL = l & 15, q16 = l >> 4, koff = q16 * 8;
    int srow = l >> 3, scol = (l & 7) * 8;     // staging sub-pattern per chunk

    floatx4 acc[4][4];
#pragma unroll
    for (int i = 0; i < 4; ++i)
#pragma unroll
        for (int j = 0; j < 4; ++j) acc[i][j] = (floatx4){0, 0, 0, 0};

    const unsigned short* gA = G    + (size_t)m_base * KFC;
    const unsigned short* gB = fcWb + (size_t)n_base * KFC;

    for (int kt = 0; kt < 16; ++kt) {
        if (kt) __syncthreads();     // previous tile's reads done before overwrite
        int k0 = kt * 64;
#pragma unroll
        for (int j = 0; j < 4; ++j) {
            int c = wv * 4 + j;
            const unsigned short* ga = gA + (size_t)(c * 8 + srow) * KFC + k0 + scol;
            const unsigned short* gb = gB + (size_t)(c * 8 + srow) * KFC + k0 + scol;
            GLD16(ga, lA + c * 512);
            GLD16(gb, lB + c * 512);
        }
        __syncthreads();             // barrier drains vmcnt -> tiles resident
#pragma unroll
        for (int ks = 0; ks < 2; ++ks) {
            const unsigned short* ap = lA + (wr * 64 + colL) * 64 + ks * 32 + koff;
            const unsigned short* bp = lB + (wc * 64 + colL) * 64 + ks * 32 + koff;
            short8 aF[4], bF[4];
#pragma unroll
            for (int ma = 0; ma < 4; ++ma) aF[ma] = ld8(ap + ma * 16 * 64);
#pragma unroll
            for (int nb = 0; nb < 4; ++nb) bF[nb] = ld8(bp + nb * 16 * 64);
#pragma unroll
            for (int ma = 0; ma < 4; ++ma)
#pragma unroll
                for (int nb = 0; nb < 4; ++nb)
                    acc[ma][nb] = mfma16(aF[ma], bF[nb], acc[ma][nb]);
        }
    }

    // ---- epilogue: per-row (max, sumexp) over this WG's 128 cols ----
    float cb[4];
#pragma unroll
    for (int nb = 0; nb < 4; ++nb)
        cb[nb] = fcb[n_base + wc * 64 + nb * 16 + colL];

#pragma unroll
    for (int ma = 0; ma < 4; ++ma) {
#pragma unroll
        for (int r = 0; r < 4; ++r) {
            float v0 = acc[ma][0][r] + cb[0];
            float v1 = acc[ma][1][r] + cb[1];
            float v2 = acc[ma][2][r] + cb[2];
            float v3 = acc[ma][3][r] + cb[3];
            float M = fmaxf(fmaxf(v0, v1), fmaxf(v2, v3));
#pragma unroll
            for (int off = 1; off < 16; off <<= 1) M = fmaxf(M, __shfl_xor(M, off, 64));
            float e = __expf(v0 - M) + __expf(v1 - M) + __expf(v2 - M) + __expf(v3 - M);
#pragma unroll
            for (int off = 1; off < 16; off <<= 1) e += __shfl_xor(e, off, 64);
            if (colL == 0)
                pbuf[wr * 64 + ma * 16 + q16 * 4 + r][wc] = make_float2(M, e);
        }
    }
    __syncthreads();
    if (tid < 128) {    // merge the two col-halves, write global partial
        float2 a = pbuf[tid][0], b = pbuf[tid][1];
        float M = fmaxf(a.x, b.x);
        float S = a.y * __expf(a.x - M) + b.y * __expf(b.x - M);
        partials[(size_t)(m_base + tid) * 250 + nwg] = make_float2(M, S);
    }
}

// 9. target logit per row: z_y = G[r] . fc_W[y] + fc_b[y]
__global__ void tgt_kernel(const unsigned short* G, const float* fcW, const float* fcb,
                           const int* X, float* tgt) {
    int r = blockIdx.x * 4 + (threadIdx.x >> 6);
    int ln = threadIdx.x & 63;
    int b = r >> 7, t = r & 127;
    int y = X[b * 129 + t + 1];
    y = (y < 0) ? 0 : ((y >= VOCAB) ? VOCAB - 1 : y);   // defensive
    const unsigned short* g = G + (size_t)r * KFC;
    const float* w = fcW + (size_t)y * KFC;
    float s = 0.f;
    for (int j = ln; j < KFC; j += 64) s += bf2f(g[j]) * w[j];
#pragma unroll
    for (int off = 32; off; off >>= 1) s += __shfl_xor(s, off, 64);
    if (ln == 0) tgt[r] = s + fcb[y];
}

// 10. merge partials -> logsumexp -> masked mean NLL
__global__ void finalize_kernel(const float2* partials, const float* tgt,
                                const int* X, float* out) {
    int tid = threadIdx.x;
    float vs = 0.f, vc = 0.f;
    for (int r = tid; r < NROW; r += 256) {
        const float2* p = partials + (size_t)r * 250;
        float M = p[0].x, S = p[0].y;
        for (int i = 1; i < 250; ++i) {
            float2 qq = p[i];
            float nm = fmaxf(M, qq.x);
            S = S * __expf(M - nm) + qq.y * __expf(qq.x - nm);
            M = nm;
        }
        float lse = M + __logf(S);
        int b = r >> 7, t = r & 127;
        int y = X[b * 129 + t + 1];
        if (y != 0) { vs += lse - tgt[r]; vc += 1.f; }
    }
    __shared__ float sv[256], sc[256];
    sv[tid] = vs; sc[tid] = vc;
    __syncthreads();
    for (int s = 128; s; s >>= 1) {
        if (tid < s) { sv[tid] += sv[tid + s]; sc[tid] += sc[tid + s]; }
        __syncthreads();
    }
    if (tid == 0) out[0] = sv[0] / sc[0];
}

// ============================================================================
// launcher
// ============================================================================
extern "C" void kernel_launch(void* const* d_in, const int* in_sizes, int n_in,
                              void* d_out, int out_size, void* d_ws, size_t ws_size,
                              hipStream_t stream) {
    const int*   X     = (const int*)d_in[0];
    const float* enc   = (const float*)d_in[2];
    const float* emb   = (const float*)d_in[3];
    const float* Wih0  = (const float*)d_in[4];
    const float* Whh0  = (const float*)d_in[5];
    const float* bih0  = (const float*)d_in[6];
    const float* bhh0  = (const float*)d_in[7];
    const float* Wih1  = (const float*)d_in[8];
    const float* Whh1  = (const float*)d_in[9];
    const float* bih1  = (const float*)d_in[10];
    const float* bhh1  = (const float*)d_in[11];
    const float* attnW = (const float*)d_in[12];
    const float* attnb = (const float*)d_in[13];
    const float* vw    = (const float*)d_in[14];
    const float* fcW   = (const float*)d_in[15];
    const float* fcb   = (const float*)d_in[16];
    const float* h0    = (const float*)d_in[17];
    const float* c0    = (const float*)d_in[18];

    char* ws = (char*)d_ws;
    size_t off = 0;
    auto take = [&](size_t bytes) { char* p = ws + off; off += (bytes + 255) & ~(size_t)255; return p; };
    int*            ctrl    = (int*)           take(12288);
    unsigned short* wih0b   = (unsigned short*)take(2097152);
    unsigned short* whh0b   = (unsigned short*)take(2097152);
    unsigned short* wih1b   = (unsigned short*)take(2097152);
    unsigned short* whh1b   = (unsigned short*)take(2097152);
    unsigned short* whb     = (unsigned short*)take(524288);
    unsigned short* web     = (unsigned short*)take(524288);
    unsigned short* encb    = (unsigned short*)take(2097152);
    unsigned short* enctb   = (unsigned short*)take(2097152);
    unsigned short* xsb     = (unsigned short*)take(2097152);
    unsigned short* h0buf   = (unsigned short*)take(32768);
    unsigned short* h1buf   = (unsigned short*)take(32768);
    unsigned short* A0b     = (unsigned short*)take(8388608);
    unsigned short* hallb   = (unsigned short*)take(2097152);
    unsigned short* gmat    = (unsigned short*)take(4194304);
    float*          ph      = (float*)         take(4194304);
    float*          pe      = (float*)         take(4194304);
    float*          logitsb = (float*)         take(1048576);
    unsigned short* attb    = (unsigned short*)take(524288);
    float2*         parts   = (float2*)        take(4096000);
    float*          tgt     = (float*)         take(8192);
    unsigned short* fcWb    = (unsigned short*)take(65536000);
    size_t need = off;
    (void)in_sizes; (void)n_in;

    if (ws_size < need) {
        // Not enough scratch: fail visibly (absmax error) instead of faulting.
        hipLaunchKernelGGL(zero_out_kernel, dim3((out_size + 63) / 64), dim3(64),
                           0, stream, (float*)d_out, out_size);
        return;
    }

    hipLaunchKernelGGL(prep_kernel, dim3(62784), dim3(256), 0, stream,
                       X, enc, emb, Wih0, Whh0, Wih1, Whh1, attnW, h0, fcW,
                       wih0b, whh0b, wih1b, whh1b, whb, web, encb, enctb,
                       xsb, h0buf, h1buf, fcWb, ctrl);
    hipLaunchKernelGGL(a0_kernel, dim3(32, 32), dim3(256), 0, stream,
                       xsb, wih0b, bih0, bhh0, A0b);
    hipLaunchKernelGGL(lstm_kernel, dim3(32), dim3(512), 0, stream,
                       A0b, whh0b, wih1b, whh1b, bih1, bhh1, c0,
                       h0buf, h1buf, hallb, gmat, ctrl);
    hipLaunchKernelGGL(phpe_kernel, dim3(32, 8, 2), dim3(256), 0, stream,
                       hallb, encb, whb, web, attnb, ph, pe);
    hipLaunchKernelGGL(logits_kernel, dim3(2048), dim3(256), 0, stream,
                       ph, pe, vw, logitsb);
    hipLaunchKernelGGL(att_kernel, dim3(128), dim3(128), 0, stream,
                       logitsb, attb);
    hipLaunchKernelGGL(weighted_kernel, dim3(2, 8, 16), dim3(256), 0, stream,
                       attb, enctb, gmat);
    hipLaunchKernelGGL(fc_kernel, dim3(250, 16), dim3(256), 0, stream,
                       gmat, fcWb, fcb, parts);
    hipLaunchKernelGGL(tgt_kernel, dim3(512), dim3(256), 0, stream,
                       gmat, fcW, fcb, X, tgt);
    hipLaunchKernelGGL(finalize_kernel, dim3(1), dim3(256), 0, stream,
                       parts, tgt, X, (float*)d_out);
}

// Round 6
// 1044.234 us; speedup vs baseline: 1.7944x; 1.7370x over previous
//
#include <hip/hip_runtime.h>

// ============================================================================
// DecoderGenerator: 2-layer LSTM decoder + additive attention + big vocab
// projection + NLL, fully fused on-device.
//
//   1. prep_kernel     : bf16-cast weights/enc/fcW, gather embeddings,
//                        transpose enc, init h-state buffers, zero flags.
//   2. a0_kernel       : A0 = xs @ W_ih0^T + b  (ROUND-1 verbatim)
//   3. lstm_kernel     : persistent 32-WG x 512-thread kernel, 129 ticks.
//                        ROUND 11: byte-exact revert to the ROUND-1 version
//                        (measured 455us). Rounds 8-10's "improvements" all
//                        regressed despite better traffic counters; the
//                        Round-1 configuration is the empirical optimum.
//   4. phpe_kernel     : ph = Hall@Wh^T ; pe = enc@We^T + attn_b
//   5. logits_kernel   : logits[t,b,l] = sum_k v_w[k] tanh(ph+pe)
//   6. att_kernel      : softmax over b (axis=1 of (T,B,L) — per reference!)
//   7. weighted_kernel : weighted = att @ enc  (per-batch GEMM) -> G[:,512:]
//   8. fc_kernel       : m97-structure 128x128xBK64 tiled GEMM + fused
//                        per-row (max,sumexp) partials.
//   9. tgt_kernel      : target logits z_y per row
//  10. row_lse_kernel  : NEW: parallel 250-way logsumexp merge (32 lanes/row)
//  11. finalize2_kernel: masked-mean NLL from lse/tgt -> d_out[0]
// ============================================================================

#define DI __device__ __forceinline__

typedef __attribute__((ext_vector_type(8))) short short8;
typedef __attribute__((ext_vector_type(4))) float floatx4;
typedef unsigned long long ull;

#define TSEQ   128
#define VOCAB  32000
#define GDIM   2048   // 4*H
#define NROW   2048   // B*T
#define KFC    1024   // 2*H
#define HPAD   520    // LDS row stride for h staging (512 + 8 pad) — ROUND-1

// ---------------- small helpers ----------------
DI float bf2f(unsigned short u) {
    union { unsigned u; float f; } x; x.u = ((unsigned)u) << 16; return x.f;
}
DI unsigned short f2bf(float f) {   // RNE float -> bf16
    unsigned u = __float_as_uint(f);
    unsigned r = (u + 0x7FFF + ((u >> 16) & 1)) >> 16;
    return (unsigned short)r;
}
DI short8 ld8(const unsigned short* p) { return *(const short8*)p; }
DI floatx4 mfma16(short8 a, short8 b, floatx4 c) {
    return __builtin_amdgcn_mfma_f32_16x16x32_bf16(a, b, c, 0, 0, 0);
}
DI float sigm(float x) { return __builtin_amdgcn_rcpf(1.f + __expf(-x)); }
DI float tanh_f(float x) {
    float xc = fminf(8.f, fmaxf(-8.f, x));
    float e  = __expf(2.f * xc);
    return (e - 1.f) * __builtin_amdgcn_rcpf(e + 1.f);
}

// async global -> LDS, 16B per lane. LDS dest must be wave-uniform base;
// lane l writes base + l*16. Global src is per-lane.
#define GLD16(gsrc, ldst)                                                     \
    __builtin_amdgcn_global_load_lds(                                         \
        (const __attribute__((address_space(1))) unsigned int*)(gsrc),        \
        (__attribute__((address_space(3))) unsigned int*)(ldst), 16, 0, 0)

// fallback path: make the failure visible instead of faulting
__global__ void zero_out_kernel(float* out, int n) {
    int i = blockIdx.x * 64 + threadIdx.x;
    if (i < n) out[i] = 0.f;
}

// ============================================================================
// 1. prep kernel : segmented grid-stride over all conversion jobs
// ============================================================================
__global__ void prep_kernel(const int* X, const float* enc, const float* emb,
                            const float* Wih0, const float* Whh0,
                            const float* Wih1, const float* Whh1,
                            const float* attnW, const float* h0,
                            const float* fcW,
                            unsigned short* wih0b, unsigned short* whh0b,
                            unsigned short* wih1b, unsigned short* whh1b,
                            unsigned short* whb, unsigned short* web,
                            unsigned short* encb, unsigned short* enctb,
                            unsigned short* xsb,
                            unsigned short* h0buf, unsigned short* h1buf,
                            unsigned short* fcWb,
                            int* ctrl) {
    if (blockIdx.x == 0) {              // zero all 3072 flag ints
#pragma unroll
        for (int j = 0; j < 12; ++j) ctrl[threadIdx.x + 256 * j] = 0;
    }
    long i = (long)blockIdx.x * 256 + threadIdx.x;
    const long NW = 1048576;
    const long NA = 262144;            // 512x512 half of attn_W
    if (i < NW) { wih0b[i] = f2bf(Wih0[i]); return; } i -= NW;
    if (i < NW) { whh0b[i] = f2bf(Whh0[i]); return; } i -= NW;
    if (i < NW) { wih1b[i] = f2bf(Wih1[i]); return; } i -= NW;
    if (i < NW) { whh1b[i] = f2bf(Whh1[i]); return; } i -= NW;
    if (i < NA) { long k = i >> 9, h = i & 511; whb[i] = f2bf(attnW[k * 1024 + h]);       return; } i -= NA;
    if (i < NA) { long k = i >> 9, h = i & 511; web[i] = f2bf(attnW[k * 1024 + 512 + h]); return; } i -= NA;
    if (i < NW) { encb[i] = f2bf(enc[i]); return; } i -= NW;
    if (i < NW) {  // enc_t[b][h][l] = enc[b][l][h]
        long b = i >> 16, r = i & 65535, h = r >> 7, l = r & 127;
        enctb[i] = f2bf(enc[(b * 128 + l) * 512 + h]); return;
    } i -= NW;
    if (i < NW) {  // xs[t*16+b][e] = emb[X[b][t]][e]
        long m = i >> 9, e = i & 511, t = m >> 4, b = m & 15;
        int xi = X[b * 129 + t];
        xi = (xi < 0) ? 0 : ((xi >= VOCAB) ? VOCAB - 1 : xi);   // defensive
        xsb[i] = f2bf(emb[(long)xi * 512 + e]); return;
    } i -= NW;
    if (i < 16384) {  // h inits into parity-1 buffers
        long layer = i >> 13, r = i & 8191;
        unsigned short v = f2bf(h0[layer * 8192 + r]);
        if (layer == 0) h0buf[8192 + r] = v; else h1buf[8192 + r] = v;
        return;
    } i -= 16384;
    if (i < 8192000) {  // fcW f32 -> bf16, 4 elements per thread
        float4 v = ((const float4*)fcW)[i];
        ushort4 o;
        o.x = f2bf(v.x); o.y = f2bf(v.y); o.z = f2bf(v.z); o.w = f2bf(v.w);
        ((ushort4*)fcWb)[i] = o;
    }
}

// ============================================================================
// shared 64x64 MFMA tile: C[m0..+63][n0..+63] += A(m,k) * B(n,k)^T
// ============================================================================
DI void gemm64_acc(const unsigned short* A, const unsigned short* Bw,
                   int m0, int n0, int lda, int ldb, int nkb, floatx4 acc[4]) {
    int tid = threadIdx.x;
    int wv = tid >> 6, ln = tid & 63;
    int colL = ln & 15, koff = (ln >> 4) * 8;
    const unsigned short* ar  = A  + (size_t)(m0 + wv * 16 + colL) * lda + koff;
    const unsigned short* br0 = Bw + (size_t)(n0 +  0 + colL) * ldb + koff;
    const unsigned short* br1 = Bw + (size_t)(n0 + 16 + colL) * ldb + koff;
    const unsigned short* br2 = Bw + (size_t)(n0 + 32 + colL) * ldb + koff;
    const unsigned short* br3 = Bw + (size_t)(n0 + 48 + colL) * ldb + koff;
    for (int kb = 0; kb < nkb; ++kb) {
        short8 af = ld8(ar + kb * 32);
        acc[0] = mfma16(af, ld8(br0 + kb * 32), acc[0]);
        acc[1] = mfma16(af, ld8(br1 + kb * 32), acc[1]);
        acc[2] = mfma16(af, ld8(br2 + kb * 32), acc[2]);
        acc[3] = mfma16(af, ld8(br3 + kb * 32), acc[3]);
    }
}

// 2. A0 = xs @ W_ih0^T + (b_ih0 + b_hh0), stored bf16 (bias folded)
//    (ROUND-1 verbatim)
__global__ void a0_kernel(const unsigned short* xs, const unsigned short* wih0b,
                          const float* bih0, const float* bhh0, unsigned short* A0b) {
    floatx4 acc[4] = {{0,0,0,0},{0,0,0,0},{0,0,0,0},{0,0,0,0}};
    int m0 = blockIdx.x * 64, n0 = blockIdx.y * 64;
    gemm64_acc(xs, wih0b, m0, n0, 512, 512, 16, acc);
    int tid = threadIdx.x, wv = tid >> 6, ln = tid & 63, colL = ln & 15, q = ln >> 4;
    int mrow = m0 + wv * 16;
#pragma unroll
    for (int nt = 0; nt < 4; ++nt) {
        int col = n0 + nt * 16 + colL;
        float bb = bih0[col] + bhh0[col];
#pragma unroll
        for (int r = 0; r < 4; ++r)
            A0b[(size_t)(mrow + q * 4 + r) * GDIM + col] = f2bf(acc[nt][r] + bb);
    }
}

// ============================================================================
// 3. persistent LSTM kernel.  32 WGs x 512 threads. (ROUND-1 verbatim: the
//    measured-best 455us configuration. Do not "improve" without A/B.)
// ============================================================================
__global__ __launch_bounds__(512, 1)
void lstm_kernel(const unsigned short* A0b,
                 const unsigned short* whh0b, const unsigned short* wih1b,
                 const unsigned short* whh1b,
                 const float* bih1, const float* bhh1, const float* c0in,
                 unsigned short* h0buf, unsigned short* h1buf,
                 unsigned short* Hall, unsigned short* Gmat, int* flags) {
    __shared__ unsigned short hsh0[16 * HPAD];   // h0[t-1], shared by both halves
    __shared__ unsigned short hsh1[16 * HPAD];   // h1[t-2], L1 half only
    __shared__ float gbuf[2][4][16][16];         // [half][gate][batch][unit]
    int wg = blockIdx.x;            // 0..31
    int tid = threadIdx.x;          // 0..511
    int half = tid >> 8;            // 0 = L0, 1 = L1
    int lt   = tid & 255;
    int wv = lt >> 6, ln = lt & 63;
    int u0 = wg * 16;
    int n0 = wv * 512 + u0;         // gate column base (wave-of-half = gate)
    int colL = ln & 15, q = ln >> 4, koff = q * 8;
    int eb = lt >> 4, eu = lt & 15; // elementwise mapping within half
    float c = c0in[half * 8192 + eb * 512 + u0 + eu];
    float bias1 = (half == 1) ? (bih1[n0 + colL] + bhh1[n0 + colL]) : 0.f;

    // ---- one-time: weight slices into registers (128 VGPRs) ----
    short8 wA[16], wB[16];
    if (half == 0) {
        const unsigned short* wr0 = whh0b + (size_t)(n0 + colL) * 512 + koff;
#pragma unroll
        for (int kb = 0; kb < 16; ++kb) wA[kb] = ld8(wr0 + kb * 32);
#pragma unroll
        for (int kb = 0; kb < 16; ++kb) wB[kb] = wA[kb];   // unused, keep defined
    } else {
        const unsigned short* wr1 = wih1b + (size_t)(n0 + colL) * 512 + koff;
        const unsigned short* wr2 = whh1b + (size_t)(n0 + colL) * 512 + koff;
#pragma unroll
        for (int kb = 0; kb < 16; ++kb) wA[kb] = ld8(wr1 + kb * 32);
#pragma unroll
        for (int kb = 0; kb < 16; ++kb) wB[kb] = ld8(wr2 + kb * 32);
    }

    // A0 prefetch for tick 0 (L0 half)
    floatx4 a0pre = {0, 0, 0, 0};
    if (half == 0) {
        const unsigned short* a0r = A0b + (size_t)0 * GDIM + n0 + colL;
        a0pre[0] = bf2f(a0r[(q * 4 + 0) * GDIM]);
        a0pre[1] = bf2f(a0r[(q * 4 + 1) * GDIM]);
        a0pre[2] = bf2f(a0r[(q * 4 + 2) * GDIM]);
        a0pre[3] = bf2f(a0r[(q * 4 + 3) * GDIM]);
    }

    // staging geometry: flat = tid*16 over [16][512]: row = tid>>5,
    // col = (tid&31)*16. 32B/thread.
    int srow = tid >> 5;
    int scol = (tid & 31) << 4;
    unsigned long long* d0 = (unsigned long long*)&hsh0[srow * HPAD + scol];
    unsigned long long* d1 = (unsigned long long*)&hsh1[srow * HPAD + scol];

#pragma unroll 1
    for (int t = 0; t <= TSEQ; ++t) {
        bool actL0 = (t < TSEQ);
        bool actL1 = (t >= 1);
        // ---- stage h vectors LLC -> LDS (relaxed agent atomics, 16KB each) ----
        {
            const unsigned long long* s0 =
                (const unsigned long long*)(h0buf + ((t - 1) & 1) * 8192) + (size_t)tid * 4;
            unsigned long long v0 = __hip_atomic_load(s0 + 0, __ATOMIC_RELAXED, __HIP_MEMORY_SCOPE_AGENT);
            unsigned long long v1 = __hip_atomic_load(s0 + 1, __ATOMIC_RELAXED, __HIP_MEMORY_SCOPE_AGENT);
            unsigned long long v2 = __hip_atomic_load(s0 + 2, __ATOMIC_RELAXED, __HIP_MEMORY_SCOPE_AGENT);
            unsigned long long v3 = __hip_atomic_load(s0 + 3, __ATOMIC_RELAXED, __HIP_MEMORY_SCOPE_AGENT);
            if (actL1) {
                const unsigned long long* s1 =
                    (const unsigned long long*)(h1buf + ((t - 2) & 1) * 8192) + (size_t)tid * 4;
                unsigned long long w0 = __hip_atomic_load(s1 + 0, __ATOMIC_RELAXED, __HIP_MEMORY_SCOPE_AGENT);
                unsigned long long w1 = __hip_atomic_load(s1 + 1, __ATOMIC_RELAXED, __HIP_MEMORY_SCOPE_AGENT);
                unsigned long long w2 = __hip_atomic_load(s1 + 2, __ATOMIC_RELAXED, __HIP_MEMORY_SCOPE_AGENT);
                unsigned long long w3 = __hip_atomic_load(s1 + 3, __ATOMIC_RELAXED, __HIP_MEMORY_SCOPE_AGENT);
                d0[0] = v0; d0[1] = v1; d0[2] = v2; d0[3] = v3;
                d1[0] = w0; d1[1] = w1; d1[2] = w2; d1[3] = w3;
            } else {
                d0[0] = v0; d0[1] = v1; d0[2] = v2; d0[3] = v3;
            }
        }
        __syncthreads();
        // ---- MFMA: LDS fragments x register weights ----
        bool act = half ? actL1 : actL0;
        if (act) {
            floatx4 acc;
            const unsigned short* hl0 = hsh0 + colL * HPAD + koff;
            if (half == 0) {
                acc = a0pre;
#pragma unroll
                for (int kb = 0; kb < 16; ++kb)
                    acc = mfma16(ld8(hl0 + kb * 32), wA[kb], acc);
            } else {
                acc[0] = bias1; acc[1] = bias1; acc[2] = bias1; acc[3] = bias1;
                const unsigned short* hl1 = hsh1 + colL * HPAD + koff;
#pragma unroll
                for (int kb = 0; kb < 16; ++kb)
                    acc = mfma16(ld8(hl0 + kb * 32), wA[kb], acc);
#pragma unroll
                for (int kb = 0; kb < 16; ++kb)
                    acc = mfma16(ld8(hl1 + kb * 32), wB[kb], acc);
            }
            // D layout: row = batch = q*4+r, col = unit = colL
            gbuf[half][wv][q * 4 + 0][colL] = acc[0];
            gbuf[half][wv][q * 4 + 1][colL] = acc[1];
            gbuf[half][wv][q * 4 + 2][colL] = acc[2];
            gbuf[half][wv][q * 4 + 3][colL] = acc[3];
        }
        __syncthreads();
        if (act) {
            float gi = gbuf[half][0][eb][eu], gf = gbuf[half][1][eb][eu];
            float gg = gbuf[half][2][eb][eu], go = gbuf[half][3][eb][eu];
            float c2 = sigm(gf) * c + sigm(gi) * tanh_f(gg);
            float h2 = sigm(go) * tanh_f(c2);
            c = c2;
            unsigned hb = (unsigned)f2bf(h2);
            unsigned up = __shfl_down(hb, 1, 64);
            unsigned packed = hb | (up << 16);
            if ((eu & 1) == 0) {
                if (half == 0) {
                    __hip_atomic_store(
                        (unsigned*)(h0buf + (t & 1) * 8192 + eb * 512 + u0 + eu),
                        packed, __ATOMIC_RELAXED, __HIP_MEMORY_SCOPE_AGENT);
                } else {
                    int s = t - 1;
                    __hip_atomic_store(
                        (unsigned*)(h1buf + (s & 1) * 8192 + eb * 512 + u0 + eu),
                        packed, __ATOMIC_RELAXED, __HIP_MEMORY_SCOPE_AGENT);
                    *(unsigned*)&Hall[(size_t)(s * 16 + eb) * 512 + u0 + eu] = packed;
                    *(unsigned*)&Gmat[(size_t)(eb * 128 + s) * KFC + u0 + eu] = packed;
                }
            }
        }
        if (t < TSEQ) {
            __syncthreads();
            if (tid == 0)
                __hip_atomic_store(flags + wg * 32, t + 1,
                                   __ATOMIC_RELAXED, __HIP_MEMORY_SCOPE_AGENT);
            if (half == 0 && t + 1 < TSEQ) {
                const unsigned short* a0r = A0b + (size_t)((t + 1) * 16) * GDIM + n0 + colL;
                a0pre[0] = bf2f(a0r[(q * 4 + 0) * GDIM]);
                a0pre[1] = bf2f(a0r[(q * 4 + 1) * GDIM]);
                a0pre[2] = bf2f(a0r[(q * 4 + 2) * GDIM]);
                a0pre[3] = bf2f(a0r[(q * 4 + 3) * GDIM]);
            }
            if (tid < 32) {
                int guard = 0;
                while (__hip_atomic_load(flags + tid * 32, __ATOMIC_RELAXED,
                                         __HIP_MEMORY_SCOPE_AGENT) < t + 1) {
                    __builtin_amdgcn_s_sleep(1);
                    if (++guard > (1 << 22)) break;   // fail loud, not hung
                }
            }
            __syncthreads();
        }
    }
}

// 4. ph = Hall @ Wh^T ; pe = enc @ We^T + attn_b   (z selects)
__global__ void phpe_kernel(const unsigned short* Hall, const unsigned short* encb,
                            const unsigned short* whb, const unsigned short* web,
                            const float* attnb, float* ph, float* pe) {
    bool ispe = (blockIdx.z != 0);
    const unsigned short* A  = ispe ? encb : Hall;
    const unsigned short* Bw = ispe ? web  : whb;
    float* out = ispe ? pe : ph;
    floatx4 acc[4] = {{0,0,0,0},{0,0,0,0},{0,0,0,0},{0,0,0,0}};
    int m0 = blockIdx.x * 64, n0 = blockIdx.y * 64;
    gemm64_acc(A, Bw, m0, n0, 512, 512, 16, acc);
    int tid = threadIdx.x, wv = tid >> 6, ln = tid & 63, colL = ln & 15, q = ln >> 4;
    int mrow = m0 + wv * 16;
#pragma unroll
    for (int nt = 0; nt < 4; ++nt) {
        int col = n0 + nt * 16 + colL;
        float bb = ispe ? attnb[col] : 0.f;
#pragma unroll
        for (int r = 0; r < 4; ++r)
            out[(size_t)(mrow + q * 4 + r) * 512 + col] = acc[nt][r] + bb;
    }
}

// 5. logits[t][l][b] = sum_k v_w[k] * tanh(ph[t*16+b][k] + pe[b*128+l][k])
__global__ void logits_kernel(const float* ph, const float* pe, const float* vw,
                              float* logits) {
    int m = blockIdx.x;             // t*16+b
    int t = m >> 4, b = m & 15;
    int tid = threadIdx.x, wv = tid >> 6, ln = tid & 63;
    const float* phr = ph + (size_t)m * 512 + ln * 8;
    floatx4 ph0 = *(const floatx4*)phr;
    floatx4 ph1 = *(const floatx4*)(phr + 4);
    const float* vwr = vw + ln * 8;
    floatx4 vw0 = *(const floatx4*)vwr;
    floatx4 vw1 = *(const floatx4*)(vwr + 4);
    for (int li = 0; li < 32; ++li) {
        int ll = wv * 32 + li;
        const float* per = pe + (size_t)(b * 128 + ll) * 512 + ln * 8;
        floatx4 p0 = *(const floatx4*)per;
        floatx4 p1 = *(const floatx4*)(per + 4);
        float s = 0.f;
#pragma unroll
        for (int j = 0; j < 4; ++j) s += vw0[j] * tanh_f(ph0[j] + p0[j]);
#pragma unroll
        for (int j = 0; j < 4; ++j) s += vw1[j] * tanh_f(ph1[j] + p1[j]);
#pragma unroll
        for (int off = 32; off; off >>= 1) s += __shfl_xor(s, off, 64);
        if (ln == 0) logits[((size_t)t * 128 + ll) * 16 + b] = s;
    }
}

// 6. softmax over b (axis=1 of (T,B,L)) -> att_bf16[b][t][l]
__global__ void att_kernel(const float* logits, unsigned short* attb) {
    int t = blockIdx.x, l = threadIdx.x;     // 128 threads
    const float* p = logits + ((size_t)t * 128 + l) * 16;
    float x[16], mx = -1e30f;
#pragma unroll
    for (int j = 0; j < 16; ++j) { x[j] = p[j]; mx = fmaxf(mx, x[j]); }
    float s = 0.f;
#pragma unroll
    for (int j = 0; j < 16; ++j) { x[j] = __expf(x[j] - mx); s += x[j]; }
    float inv = __builtin_amdgcn_rcpf(s);
#pragma unroll
    for (int j = 0; j < 16; ++j)
        attb[((size_t)j * 128 + t) * 128 + l] = f2bf(x[j] * inv);
}

// 7. weighted[b][t][h] = att[b] @ enc[b]  ->  G[b*128+t][512+h]
__global__ void weighted_kernel(const unsigned short* attb, const unsigned short* enctb,
                                unsigned short* Gmat) {
    int b = blockIdx.z;
    floatx4 acc[4] = {{0,0,0,0},{0,0,0,0},{0,0,0,0},{0,0,0,0}};
    int m0 = blockIdx.x * 64, n0 = blockIdx.y * 64;
    gemm64_acc(attb + (size_t)b * 128 * 128, enctb + (size_t)b * 512 * 128,
               m0, n0, 128, 128, 4, acc);
    int tid = threadIdx.x, wv = tid >> 6, ln = tid & 63, colL = ln & 15, q = ln >> 4;
    int mrow = m0 + wv * 16;
#pragma unroll
    for (int nt = 0; nt < 4; ++nt) {
        int col = n0 + nt * 16 + colL;
#pragma unroll
        for (int r = 0; r < 4; ++r)
            Gmat[(size_t)(b * 128 + mrow + q * 4 + r) * KFC + 512 + col] = f2bf(acc[nt][r]);
    }
}

// ============================================================================
// 8. fc GEMM (m97-structure) + fused per-row (max, sumexp) partials.
// ============================================================================
__global__ __launch_bounds__(256)
void fc_kernel(const unsigned short* G, const unsigned short* fcWb,
               const float* fcb, float2* partials) {
    __shared__ __align__(16) unsigned short lA[128 * 64];
    __shared__ __align__(16) unsigned short lB[128 * 64];
    __shared__ float2 pbuf[128][2];
    int nwg = blockIdx.x;            // 0..249
    int mwg = blockIdx.y;            // 0..15
    int n_base = nwg * 128, m_base = mwg * 128;
    int tid = threadIdx.x, wv = tid >> 6, l = tid & 63;
    int wr = wv >> 1, wc = wv & 1;
    int colL = l & 15, q16 = l >> 4, koff = q16 * 8;
    int srow = l >> 3, scol = (l & 7) * 8;     // staging sub-pattern per chunk

    floatx4 acc[4][4];
#pragma unroll
    for (int i = 0; i < 4; ++i)
#pragma unroll
        for (int j = 0; j < 4; ++j) acc[i][j] = (floatx4){0, 0, 0, 0};

    const unsigned short* gA = G    + (size_t)m_base * KFC;
    const unsigned short* gB = fcWb + (size_t)n_base * KFC;

    for (int kt = 0; kt < 16; ++kt) {
        if (kt) __syncthreads();     // previous tile's reads done before overwrite
        int k0 = kt * 64;
#pragma unroll
        for (int j = 0; j < 4; ++j) {
            int c = wv * 4 + j;
            const unsigned short* ga = gA + (size_t)(c * 8 + srow) * KFC + k0 + scol;
            const unsigned short* gb = gB + (size_t)(c * 8 + srow) * KFC + k0 + scol;
            GLD16(ga, lA + c * 512);
            GLD16(gb, lB + c * 512);
        }
        __syncthreads();             // barrier drains vmcnt -> tiles resident
#pragma unroll
        for (int ks = 0; ks < 2; ++ks) {
            const unsigned short* ap = lA + (wr * 64 + colL) * 64 + ks * 32 + koff;
            const unsigned short* bp = lB + (wc * 64 + colL) * 64 + ks * 32 + koff;
            short8 aF[4], bF[4];
#pragma unroll
            for (int ma = 0; ma < 4; ++ma) aF[ma] = ld8(ap + ma * 16 * 64);
#pragma unroll
            for (int nb = 0; nb < 4; ++nb) bF[nb] = ld8(bp + nb * 16 * 64);
#pragma unroll
            for (int ma = 0; ma < 4; ++ma)
#pragma unroll
                for (int nb = 0; nb < 4; ++nb)
                    acc[ma][nb] = mfma16(aF[ma], bF[nb], acc[ma][nb]);
        }
    }

    // ---- epilogue: per-row (max, sumexp) over this WG's 128 cols ----
    float cb[4];
#pragma unroll
    for (int nb = 0; nb < 4; ++nb)
        cb[nb] = fcb[n_base + wc * 64 + nb * 16 + colL];

#pragma unroll
    for (int ma = 0; ma < 4; ++ma) {
#pragma unroll
        for (int r = 0; r < 4; ++r) {
            float v0 = acc[ma][0][r] + cb[0];
            float v1 = acc[ma][1][r] + cb[1];
            float v2 = acc[ma][2][r] + cb[2];
            float v3 = acc[ma][3][r] + cb[3];
            float M = fmaxf(fmaxf(v0, v1), fmaxf(v2, v3));
#pragma unroll
            for (int off = 1; off < 16; off <<= 1) M = fmaxf(M, __shfl_xor(M, off, 64));
            float e = __expf(v0 - M) + __expf(v1 - M) + __expf(v2 - M) + __expf(v3 - M);
#pragma unroll
            for (int off = 1; off < 16; off <<= 1) e += __shfl_xor(e, off, 64);
            if (colL == 0)
                pbuf[wr * 64 + ma * 16 + q16 * 4 + r][wc] = make_float2(M, e);
        }
    }
    __syncthreads();
    if (tid < 128) {    // merge the two col-halves, write global partial
        float2 a = pbuf[tid][0], b = pbuf[tid][1];
        float M = fmaxf(a.x, b.x);
        float S = a.y * __expf(a.x - M) + b.y * __expf(b.x - M);
        partials[(size_t)(m_base + tid) * 250 + nwg] = make_float2(M, S);
    }
}

// 9. target logit per row: z_y = G[r] . fc_W[y] + fc_b[y]
__global__ void tgt_kernel(const unsigned short* G, const float* fcW, const float* fcb,
                           const int* X, float* tgt) {
    int r = blockIdx.x * 4 + (threadIdx.x >> 6);
    int ln = threadIdx.x & 63;
    int b = r >> 7, t = r & 127;
    int y = X[b * 129 + t + 1];
    y = (y < 0) ? 0 : ((y >= VOCAB) ? VOCAB - 1 : y);   // defensive
    const unsigned short* g = G + (size_t)r * KFC;
    const float* w = fcW + (size_t)y * KFC;
    float s = 0.f;
    for (int j = ln; j < KFC; j += 64) s += bf2f(g[j]) * w[j];
#pragma unroll
    for (int off = 32; off; off >>= 1) s += __shfl_xor(s, off, 64);
    if (ln == 0) tgt[r] = s + fcb[y];
}

// 10. parallel logsumexp merge: 32 lanes per row over 250 partials.
//     (M,S) merge is associative+commutative -> strided + butterfly reduce.
__global__ void row_lse_kernel(const float2* partials, float* lse) {
    int row = blockIdx.x * 8 + (threadIdx.x >> 5);   // 256 blocks x 8 rows
    int ln = threadIdx.x & 31;
    const float2* p = partials + (size_t)row * 250;
    float M = -1e30f, S = 0.f;
    for (int i = ln; i < 250; i += 32) {
        float2 q = p[i];
        float nm = fmaxf(M, q.x);
        S = S * __expf(M - nm) + q.y * __expf(q.x - nm);
        M = nm;
    }
#pragma unroll
    for (int off = 16; off; off >>= 1) {
        float Mo = __shfl_xor(M, off, 64);
        float So = __shfl_xor(S, off, 64);
        float nm = fmaxf(M, Mo);
        S = S * __expf(M - nm) + So * __expf(Mo - nm);
        M = nm;
    }
    if (ln == 0) lse[row] = M + __logf(S);
}

// 11. masked-mean NLL from lse/tgt
__global__ void finalize2_kernel(const float* lse, const float* tgt,
                                 const int* X, float* out) {
    int tid = threadIdx.x;
    float vs = 0.f, vc = 0.f;
    for (int r = tid; r < NROW; r += 256) {
        int b = r >> 7, t = r & 127;
        int y = X[b * 129 + t + 1];
        if (y != 0) { vs += lse[r] - tgt[r]; vc += 1.f; }
    }
    __shared__ float sv[256], sc[256];
    sv[tid] = vs; sc[tid] = vc;
    __syncthreads();
    for (int s = 128; s; s >>= 1) {
        if (tid < s) { sv[tid] += sv[tid + s]; sc[tid] += sc[tid + s]; }
        __syncthreads();
    }
    if (tid == 0) out[0] = sv[0] / sc[0];
}

// ============================================================================
// launcher
// ============================================================================
extern "C" void kernel_launch(void* const* d_in, const int* in_sizes, int n_in,
                              void* d_out, int out_size, void* d_ws, size_t ws_size,
                              hipStream_t stream) {
    const int*   X     = (const int*)d_in[0];
    const float* enc   = (const float*)d_in[2];
    const float* emb   = (const float*)d_in[3];
    const float* Wih0  = (const float*)d_in[4];
    const float* Whh0  = (const float*)d_in[5];
    const float* bih0  = (const float*)d_in[6];
    const float* bhh0  = (const float*)d_in[7];
    const float* Wih1  = (const float*)d_in[8];
    const float* Whh1  = (const float*)d_in[9];
    const float* bih1  = (const float*)d_in[10];
    const float* bhh1  = (const float*)d_in[11];
    const float* attnW = (const float*)d_in[12];
    const float* attnb = (const float*)d_in[13];
    const float* vw    = (const float*)d_in[14];
    const float* fcW   = (const float*)d_in[15];
    const float* fcb   = (const float*)d_in[16];
    const float* h0    = (const float*)d_in[17];
    const float* c0    = (const float*)d_in[18];

    char* ws = (char*)d_ws;
    size_t off = 0;
    auto take = [&](size_t bytes) { char* p = ws + off; off += (bytes + 255) & ~(size_t)255; return p; };
    int*            ctrl    = (int*)           take(12288);
    unsigned short* wih0b   = (unsigned short*)take(2097152);
    unsigned short* whh0b   = (unsigned short*)take(2097152);
    unsigned short* wih1b   = (unsigned short*)take(2097152);
    unsigned short* whh1b   = (unsigned short*)take(2097152);
    unsigned short* whb     = (unsigned short*)take(524288);
    unsigned short* web     = (unsigned short*)take(524288);
    unsigned short* encb    = (unsigned short*)take(2097152);
    unsigned short* enctb   = (unsigned short*)take(2097152);
    unsigned short* xsb     = (unsigned short*)take(2097152);
    unsigned short* h0buf   = (unsigned short*)take(32768);
    unsigned short* h1buf   = (unsigned short*)take(32768);
    unsigned short* A0b     = (unsigned short*)take(8388608);
    unsigned short* hallb   = (unsigned short*)take(2097152);
    unsigned short* gmat    = (unsigned short*)take(4194304);
    float*          ph      = (float*)         take(4194304);
    float*          pe      = (float*)         take(4194304);
    float*          logitsb = (float*)         take(1048576);
    unsigned short* attb    = (unsigned short*)take(524288);
    float2*         parts   = (float2*)        take(4096000);
    float*          tgt     = (float*)         take(8192);
    float*          lseb    = (float*)         take(8192);
    unsigned short* fcWb    = (unsigned short*)take(65536000);
    size_t need = off;
    (void)in_sizes; (void)n_in;

    if (ws_size < need) {
        // Not enough scratch: fail visibly (absmax error) instead of faulting.
        hipLaunchKernelGGL(zero_out_kernel, dim3((out_size + 63) / 64), dim3(64),
                           0, stream, (float*)d_out, out_size);
        return;
    }

    hipLaunchKernelGGL(prep_kernel, dim3(62784), dim3(256), 0, stream,
                       X, enc, emb, Wih0, Whh0, Wih1, Whh1, attnW, h0, fcW,
                       wih0b, whh0b, wih1b, whh1b, whb, web, encb, enctb,
                       xsb, h0buf, h1buf, fcWb, ctrl);
    hipLaunchKernelGGL(a0_kernel, dim3(32, 32), dim3(256), 0, stream,
                       xsb, wih0b, bih0, bhh0, A0b);
    hipLaunchKernelGGL(lstm_kernel, dim3(32), dim3(512), 0, stream,
                       A0b, whh0b, wih1b, whh1b, bih1, bhh1, c0,
                       h0buf, h1buf, hallb, gmat, ctrl);
    hipLaunchKernelGGL(phpe_kernel, dim3(32, 8, 2), dim3(256), 0, stream,
                       hallb, encb, whb, web, attnb, ph, pe);
    hipLaunchKernelGGL(logits_kernel, dim3(2048), dim3(256), 0, stream,
                       ph, pe, vw, logitsb);
    hipLaunchKernelGGL(att_kernel, dim3(128), dim3(128), 0, stream,
                       logitsb, attb);
    hipLaunchKernelGGL(weighted_kernel, dim3(2, 8, 16), dim3(256), 0, stream,
                       attb, enctb, gmat);
    hipLaunchKernelGGL(fc_kernel, dim3(250, 16), dim3(256), 0, stream,
                       gmat, fcWb, fcb, parts);
    hipLaunchKernelGGL(tgt_kernel, dim3(512), dim3(256), 0, stream,
                       gmat, fcW, fcb, X, tgt);
    hipLaunchKernelGGL(row_lse_kernel, dim3(256), dim3(256), 0, stream,
                       parts, lseb);
    hipLaunchKernelGGL(finalize2_kernel, dim3(1), dim3(256), 0, stream,
                       lseb, tgt, X, (float*)d_out);
}

// Round 7
// 988.127 us; speedup vs baseline: 1.8963x; 1.0568x over previous
//
#include <hip/hip_runtime.h>

// ============================================================================
// DecoderGenerator: 2-layer LSTM decoder + additive attention + big vocab
// projection + NLL, fully fused on-device.
//
//   1. prep_kernel     : bf16-cast weights/enc, gather embeddings, transpose
//                        enc, init h-state buffers, zero flags. (fcW moved
//                        to lstm freeloader WGs.)
//   2. a0_kernel       : A0 = xs @ W_ih0^T + b  (hoisted layer-0 input GEMM)
//   3. lstm_kernel     : persistent kernel, 256 WGs x 512 threads.
//                        WGs 0..31  : ROUND-1 LSTM loop (measured 441us) with
//                                     ONE change: all-thread flag poll,
//                                     barrier #4 removed (A0 prefetch now
//                                     stays in flight to its use).
//                        WGs 32..255: freeloaders — convert fcW f32->bf16
//                                     in the LSTM's shadow (224 idle CUs).
//   4. phpe_kernel     : ph = Hall@Wh^T ; pe = enc@We^T + attn_b
//   5. logits_kernel   : logits[t,b,l] = sum_k v_w[k] tanh(ph+pe)
//   6. att_kernel      : softmax over b (axis=1 of (T,B,L) — per reference!)
//   7. weighted_kernel : weighted = att @ enc  (per-batch GEMM) -> G[:,512:]
//   8. fc_kernel       : m97-structure 128x128xBK64 tiled GEMM + fused
//                        per-row (max,sumexp) partials.
//   9. tgt_kernel      : target logits z_y per row
//  10. row_lse_kernel  : parallel 250-way logsumexp merge (32 lanes/row)
//  11. finalize2_kernel: masked-mean NLL from lse/tgt -> d_out[0]
// ============================================================================

#define DI __device__ __forceinline__

typedef __attribute__((ext_vector_type(8))) short short8;
typedef __attribute__((ext_vector_type(4))) float floatx4;
typedef unsigned long long ull;

#define TSEQ   128
#define VOCAB  32000
#define GDIM   2048   // 4*H
#define NROW   2048   // B*T
#define KFC    1024   // 2*H
#define HPAD   520    // LDS row stride for h staging (512 + 8 pad) — ROUND-1

// ---------------- small helpers ----------------
DI float bf2f(unsigned short u) {
    union { unsigned u; float f; } x; x.u = ((unsigned)u) << 16; return x.f;
}
DI unsigned short f2bf(float f) {   // RNE float -> bf16
    unsigned u = __float_as_uint(f);
    unsigned r = (u + 0x7FFF + ((u >> 16) & 1)) >> 16;
    return (unsigned short)r;
}
DI short8 ld8(const unsigned short* p) { return *(const short8*)p; }
DI floatx4 mfma16(short8 a, short8 b, floatx4 c) {
    return __builtin_amdgcn_mfma_f32_16x16x32_bf16(a, b, c, 0, 0, 0);
}
DI float sigm(float x) { return __builtin_amdgcn_rcpf(1.f + __expf(-x)); }
DI float tanh_f(float x) {
    float xc = fminf(8.f, fmaxf(-8.f, x));
    float e  = __expf(2.f * xc);
    return (e - 1.f) * __builtin_amdgcn_rcpf(e + 1.f);
}

// async global -> LDS, 16B per lane. LDS dest must be wave-uniform base;
// lane l writes base + l*16. Global src is per-lane.
#define GLD16(gsrc, ldst)                                                     \
    __builtin_amdgcn_global_load_lds(                                         \
        (const __attribute__((address_space(1))) unsigned int*)(gsrc),        \
        (__attribute__((address_space(3))) unsigned int*)(ldst), 16, 0, 0)

// fallback path: make the failure visible instead of faulting
__global__ void zero_out_kernel(float* out, int n) {
    int i = blockIdx.x * 64 + threadIdx.x;
    if (i < n) out[i] = 0.f;
}

// ============================================================================
// 1. prep kernel : segmented grid-stride over all conversion jobs
//    total work = 4*1048576 + 2*262144 + 3*1048576 + 16384 = 7,880,704
//    grid = 30784 blocks x 256.  (fcW conversion lives in lstm freeloaders.)
// ============================================================================
__global__ void prep_kernel(const int* X, const float* enc, const float* emb,
                            const float* Wih0, const float* Whh0,
                            const float* Wih1, const float* Whh1,
                            const float* attnW, const float* h0,
                            unsigned short* wih0b, unsigned short* whh0b,
                            unsigned short* wih1b, unsigned short* whh1b,
                            unsigned short* whb, unsigned short* web,
                            unsigned short* encb, unsigned short* enctb,
                            unsigned short* xsb,
                            unsigned short* h0buf, unsigned short* h1buf,
                            int* ctrl) {
    if (blockIdx.x == 0) {              // zero all 3072 flag ints
#pragma unroll
        for (int j = 0; j < 12; ++j) ctrl[threadIdx.x + 256 * j] = 0;
    }
    long i = (long)blockIdx.x * 256 + threadIdx.x;
    const long NW = 1048576;
    const long NA = 262144;            // 512x512 half of attn_W
    if (i < NW) { wih0b[i] = f2bf(Wih0[i]); return; } i -= NW;
    if (i < NW) { whh0b[i] = f2bf(Whh0[i]); return; } i -= NW;
    if (i < NW) { wih1b[i] = f2bf(Wih1[i]); return; } i -= NW;
    if (i < NW) { whh1b[i] = f2bf(Whh1[i]); return; } i -= NW;
    if (i < NA) { long k = i >> 9, h = i & 511; whb[i] = f2bf(attnW[k * 1024 + h]);       return; } i -= NA;
    if (i < NA) { long k = i >> 9, h = i & 511; web[i] = f2bf(attnW[k * 1024 + 512 + h]); return; } i -= NA;
    if (i < NW) { encb[i] = f2bf(enc[i]); return; } i -= NW;
    if (i < NW) {  // enc_t[b][h][l] = enc[b][l][h]
        long b = i >> 16, r = i & 65535, h = r >> 7, l = r & 127;
        enctb[i] = f2bf(enc[(b * 128 + l) * 512 + h]); return;
    } i -= NW;
    if (i < NW) {  // xs[t*16+b][e] = emb[X[b][t]][e]
        long m = i >> 9, e = i & 511, t = m >> 4, b = m & 15;
        int xi = X[b * 129 + t];
        xi = (xi < 0) ? 0 : ((xi >= VOCAB) ? VOCAB - 1 : xi);   // defensive
        xsb[i] = f2bf(emb[(long)xi * 512 + e]); return;
    } i -= NW;
    if (i < 16384) {  // h inits into parity-1 buffers
        long layer = i >> 13, r = i & 8191;
        unsigned short v = f2bf(h0[layer * 8192 + r]);
        if (layer == 0) h0buf[8192 + r] = v; else h1buf[8192 + r] = v;
    }
}

// ============================================================================
// shared 64x64 MFMA tile: C[m0..+63][n0..+63] += A(m,k) * B(n,k)^T
// ============================================================================
DI void gemm64_acc(const unsigned short* A, const unsigned short* Bw,
                   int m0, int n0, int lda, int ldb, int nkb, floatx4 acc[4]) {
    int tid = threadIdx.x;
    int wv = tid >> 6, ln = tid & 63;
    int colL = ln & 15, koff = (ln >> 4) * 8;
    const unsigned short* ar  = A  + (size_t)(m0 + wv * 16 + colL) * lda + koff;
    const unsigned short* br0 = Bw + (size_t)(n0 +  0 + colL) * ldb + koff;
    const unsigned short* br1 = Bw + (size_t)(n0 + 16 + colL) * ldb + koff;
    const unsigned short* br2 = Bw + (size_t)(n0 + 32 + colL) * ldb + koff;
    const unsigned short* br3 = Bw + (size_t)(n0 + 48 + colL) * ldb + koff;
    for (int kb = 0; kb < nkb; ++kb) {
        short8 af = ld8(ar + kb * 32);
        acc[0] = mfma16(af, ld8(br0 + kb * 32), acc[0]);
        acc[1] = mfma16(af, ld8(br1 + kb * 32), acc[1]);
        acc[2] = mfma16(af, ld8(br2 + kb * 32), acc[2]);
        acc[3] = mfma16(af, ld8(br3 + kb * 32), acc[3]);
    }
}

// 2. A0 = xs @ W_ih0^T + (b_ih0 + b_hh0), stored bf16 (bias folded)
__global__ void a0_kernel(const unsigned short* xs, const unsigned short* wih0b,
                          const float* bih0, const float* bhh0, unsigned short* A0b) {
    floatx4 acc[4] = {{0,0,0,0},{0,0,0,0},{0,0,0,0},{0,0,0,0}};
    int m0 = blockIdx.x * 64, n0 = blockIdx.y * 64;
    gemm64_acc(xs, wih0b, m0, n0, 512, 512, 16, acc);
    int tid = threadIdx.x, wv = tid >> 6, ln = tid & 63, colL = ln & 15, q = ln >> 4;
    int mrow = m0 + wv * 16;
#pragma unroll
    for (int nt = 0; nt < 4; ++nt) {
        int col = n0 + nt * 16 + colL;
        float bb = bih0[col] + bhh0[col];
#pragma unroll
        for (int r = 0; r < 4; ++r)
            A0b[(size_t)(mrow + q * 4 + r) * GDIM + col] = f2bf(acc[nt][r] + bb);
    }
}

// ============================================================================
// 3. persistent LSTM kernel.  256 WGs x 512 threads.
//    WGs 0..31: ROUND-1 LSTM (441us measured) + all-thread poll (bar #4
//    removed; A0 prefetch stays in flight until its MFMA use).
//    WGs 32..255: fcW f32->bf16 freeloaders (no flags, no barriers).
// ============================================================================
__global__ __launch_bounds__(512, 1)
void lstm_kernel(const unsigned short* A0b,
                 const unsigned short* whh0b, const unsigned short* wih1b,
                 const unsigned short* whh1b,
                 const float* bih1, const float* bhh1, const float* c0in,
                 unsigned short* h0buf, unsigned short* h1buf,
                 unsigned short* Hall, unsigned short* Gmat, int* flags,
                 const float* fcW, unsigned short* fcWb) {
    int wg = blockIdx.x;            // 0..255
    int tid = threadIdx.x;          // 0..511

    if (wg >= 32) {
        // -------- freeloader: convert fcW while the LSTM runs --------
        const float4* src = (const float4*)fcW;
        ushort4* dst = (ushort4*)fcWb;
        for (long i = (long)(wg - 32) * 512 + tid; i < 8192000; i += 224 * 512) {
            float4 v = src[i];
            ushort4 o;
            o.x = f2bf(v.x); o.y = f2bf(v.y); o.z = f2bf(v.z); o.w = f2bf(v.w);
            dst[i] = o;
        }
        return;
    }

    __shared__ unsigned short hsh0[16 * HPAD];   // h0[t-1], shared by both halves
    __shared__ unsigned short hsh1[16 * HPAD];   // h1[t-2], L1 half only
    __shared__ float gbuf[2][4][16][16];         // [half][gate][batch][unit]
    int half = tid >> 8;            // 0 = L0, 1 = L1
    int lt   = tid & 255;
    int wv = lt >> 6, ln = lt & 63;
    int u0 = wg * 16;
    int n0 = wv * 512 + u0;         // gate column base (wave-of-half = gate)
    int colL = ln & 15, q = ln >> 4, koff = q * 8;
    int eb = lt >> 4, eu = lt & 15; // elementwise mapping within half
    float c = c0in[half * 8192 + eb * 512 + u0 + eu];
    float bias1 = (half == 1) ? (bih1[n0 + colL] + bhh1[n0 + colL]) : 0.f;

    // ---- one-time: weight slices into registers (128 VGPRs) ----
    short8 wA[16], wB[16];
    if (half == 0) {
        const unsigned short* wr0 = whh0b + (size_t)(n0 + colL) * 512 + koff;
#pragma unroll
        for (int kb = 0; kb < 16; ++kb) wA[kb] = ld8(wr0 + kb * 32);
#pragma unroll
        for (int kb = 0; kb < 16; ++kb) wB[kb] = wA[kb];   // unused, keep defined
    } else {
        const unsigned short* wr1 = wih1b + (size_t)(n0 + colL) * 512 + koff;
        const unsigned short* wr2 = whh1b + (size_t)(n0 + colL) * 512 + koff;
#pragma unroll
        for (int kb = 0; kb < 16; ++kb) wA[kb] = ld8(wr1 + kb * 32);
#pragma unroll
        for (int kb = 0; kb < 16; ++kb) wB[kb] = ld8(wr2 + kb * 32);
    }

    // A0 prefetch for tick 0 (L0 half)
    floatx4 a0pre = {0, 0, 0, 0};
    if (half == 0) {
        const unsigned short* a0r = A0b + (size_t)0 * GDIM + n0 + colL;
        a0pre[0] = bf2f(a0r[(q * 4 + 0) * GDIM]);
        a0pre[1] = bf2f(a0r[(q * 4 + 1) * GDIM]);
        a0pre[2] = bf2f(a0r[(q * 4 + 2) * GDIM]);
        a0pre[3] = bf2f(a0r[(q * 4 + 3) * GDIM]);
    }

    // staging geometry: flat = tid*16 over [16][512]: row = tid>>5,
    // col = (tid&31)*16. 32B/thread.
    int srow = tid >> 5;
    int scol = (tid & 31) << 4;
    unsigned long long* d0 = (unsigned long long*)&hsh0[srow * HPAD + scol];
    unsigned long long* d1 = (unsigned long long*)&hsh1[srow * HPAD + scol];

#pragma unroll 1
    for (int t = 0; t <= TSEQ; ++t) {
        bool actL0 = (t < TSEQ);
        bool actL1 = (t >= 1);
        // ---- stage h vectors LLC -> LDS (relaxed agent atomics, 16KB each) ----
        {
            const unsigned long long* s0 =
                (const unsigned long long*)(h0buf + ((t - 1) & 1) * 8192) + (size_t)tid * 4;
            unsigned long long v0 = __hip_atomic_load(s0 + 0, __ATOMIC_RELAXED, __HIP_MEMORY_SCOPE_AGENT);
            unsigned long long v1 = __hip_atomic_load(s0 + 1, __ATOMIC_RELAXED, __HIP_MEMORY_SCOPE_AGENT);
            unsigned long long v2 = __hip_atomic_load(s0 + 2, __ATOMIC_RELAXED, __HIP_MEMORY_SCOPE_AGENT);
            unsigned long long v3 = __hip_atomic_load(s0 + 3, __ATOMIC_RELAXED, __HIP_MEMORY_SCOPE_AGENT);
            if (actL1) {
                const unsigned long long* s1 =
                    (const unsigned long long*)(h1buf + ((t - 2) & 1) * 8192) + (size_t)tid * 4;
                unsigned long long w0 = __hip_atomic_load(s1 + 0, __ATOMIC_RELAXED, __HIP_MEMORY_SCOPE_AGENT);
                unsigned long long w1 = __hip_atomic_load(s1 + 1, __ATOMIC_RELAXED, __HIP_MEMORY_SCOPE_AGENT);
                unsigned long long w2 = __hip_atomic_load(s1 + 2, __ATOMIC_RELAXED, __HIP_MEMORY_SCOPE_AGENT);
                unsigned long long w3 = __hip_atomic_load(s1 + 3, __ATOMIC_RELAXED, __HIP_MEMORY_SCOPE_AGENT);
                d0[0] = v0; d0[1] = v1; d0[2] = v2; d0[3] = v3;
                d1[0] = w0; d1[1] = w1; d1[2] = w2; d1[3] = w3;
            } else {
                d0[0] = v0; d0[1] = v1; d0[2] = v2; d0[3] = v3;
            }
        }
        __syncthreads();
        // ---- MFMA: LDS fragments x register weights ----
        bool act = half ? actL1 : actL0;
        if (act) {
            floatx4 acc;
            const unsigned short* hl0 = hsh0 + colL * HPAD + koff;
            if (half == 0) {
                acc = a0pre;
#pragma unroll
                for (int kb = 0; kb < 16; ++kb)
                    acc = mfma16(ld8(hl0 + kb * 32), wA[kb], acc);
            } else {
                acc[0] = bias1; acc[1] = bias1; acc[2] = bias1; acc[3] = bias1;
                const unsigned short* hl1 = hsh1 + colL * HPAD + koff;
#pragma unroll
                for (int kb = 0; kb < 16; ++kb)
                    acc = mfma16(ld8(hl0 + kb * 32), wA[kb], acc);
#pragma unroll
                for (int kb = 0; kb < 16; ++kb)
                    acc = mfma16(ld8(hl1 + kb * 32), wB[kb], acc);
            }
            // D layout: row = batch = q*4+r, col = unit = colL
            gbuf[half][wv][q * 4 + 0][colL] = acc[0];
            gbuf[half][wv][q * 4 + 1][colL] = acc[1];
            gbuf[half][wv][q * 4 + 2][colL] = acc[2];
            gbuf[half][wv][q * 4 + 3][colL] = acc[3];
        }
        __syncthreads();
        if (act) {
            float gi = gbuf[half][0][eb][eu], gf = gbuf[half][1][eb][eu];
            float gg = gbuf[half][2][eb][eu], go = gbuf[half][3][eb][eu];
            float c2 = sigm(gf) * c + sigm(gi) * tanh_f(gg);
            float h2 = sigm(go) * tanh_f(c2);
            c = c2;
            unsigned hb = (unsigned)f2bf(h2);
            unsigned up = __shfl_down(hb, 1, 64);
            unsigned packed = hb | (up << 16);
            if ((eu & 1) == 0) {
                if (half == 0) {
                    __hip_atomic_store(
                        (unsigned*)(h0buf + (t & 1) * 8192 + eb * 512 + u0 + eu),
                        packed, __ATOMIC_RELAXED, __HIP_MEMORY_SCOPE_AGENT);
                } else {
                    int s = t - 1;
                    __hip_atomic_store(
                        (unsigned*)(h1buf + (s & 1) * 8192 + eb * 512 + u0 + eu),
                        packed, __ATOMIC_RELAXED, __HIP_MEMORY_SCOPE_AGENT);
                    *(unsigned*)&Hall[(size_t)(s * 16 + eb) * 512 + u0 + eu] = packed;
                    *(unsigned*)&Gmat[(size_t)(eb * 128 + s) * KFC + u0 + eu] = packed;
                }
            }
        }
        if (t < TSEQ) {
            // publish: __syncthreads drains all waves' vmem (hipcc emits
            // s_waitcnt vmcnt(0) before s_barrier) -> h-stores LLC-visible.
            __syncthreads();
            if (tid == 0)
                __hip_atomic_store(flags + wg * 32, t + 1,
                                   __ATOMIC_RELAXED, __HIP_MEMORY_SCOPE_AGENT);
            // prefetch next tick's A0 now — with bar #4 gone it stays in
            // flight until its use in the next MFMA phase.
            if (half == 0 && t + 1 < TSEQ) {
                const unsigned short* a0r = A0b + (size_t)((t + 1) * 16) * GDIM + n0 + colL;
                a0pre[0] = bf2f(a0r[(q * 4 + 0) * GDIM]);
                a0pre[1] = bf2f(a0r[(q * 4 + 1) * GDIM]);
                a0pre[2] = bf2f(a0r[(q * 4 + 2) * GDIM]);
                a0pre[3] = bf2f(a0r[(q * 4 + 3) * GDIM]);
            }
            // ALL threads poll (self-detect; no broadcast barrier needed:
            // after the publish barrier hsh0/hsh1/gbuf are dead until
            // restaged, and staging is control-dependent on this loop).
            {
                int* f = flags + (tid & 31) * 32;
                int g = 0;
                while (__hip_atomic_load(f, __ATOMIC_RELAXED,
                                         __HIP_MEMORY_SCOPE_AGENT) < t + 1) {
                    __builtin_amdgcn_s_sleep(1);
                    if (++g > (1 << 22)) break;   // fail loud, not hung
                }
                asm volatile("" ::: "memory");    // no load hoisting past poll
            }
        }
    }
}

// 4. ph = Hall @ Wh^T ; pe = enc @ We^T + attn_b   (z selects)
__global__ void phpe_kernel(const unsigned short* Hall, const unsigned short* encb,
                            const unsigned short* whb, const unsigned short* web,
                            const float* attnb, float* ph, float* pe) {
    bool ispe = (blockIdx.z != 0);
    const unsigned short* A  = ispe ? encb : Hall;
    const unsigned short* Bw = ispe ? web  : whb;
    float* out = ispe ? pe : ph;
    floatx4 acc[4] = {{0,0,0,0},{0,0,0,0},{0,0,0,0},{0,0,0,0}};
    int m0 = blockIdx.x * 64, n0 = blockIdx.y * 64;
    gemm64_acc(A, Bw, m0, n0, 512, 512, 16, acc);
    int tid = threadIdx.x, wv = tid >> 6, ln = tid & 63, colL = ln & 15, q = ln >> 4;
    int mrow = m0 + wv * 16;
#pragma unroll
    for (int nt = 0; nt < 4; ++nt) {
        int col = n0 + nt * 16 + colL;
        float bb = ispe ? attnb[col] : 0.f;
#pragma unroll
        for (int r = 0; r < 4; ++r)
            out[(size_t)(mrow + q * 4 + r) * 512 + col] = acc[nt][r] + bb;
    }
}

// 5. logits[t][l][b] = sum_k v_w[k] * tanh(ph[t*16+b][k] + pe[b*128+l][k])
__global__ void logits_kernel(const float* ph, const float* pe, const float* vw,
                              float* logits) {
    int m = blockIdx.x;             // t*16+b
    int t = m >> 4, b = m & 15;
    int tid = threadIdx.x, wv = tid >> 6, ln = tid & 63;
    const float* phr = ph + (size_t)m * 512 + ln * 8;
    floatx4 ph0 = *(const floatx4*)phr;
    floatx4 ph1 = *(const floatx4*)(phr + 4);
    const float* vwr = vw + ln * 8;
    floatx4 vw0 = *(const floatx4*)vwr;
    floatx4 vw1 = *(const floatx4*)(vwr + 4);
    for (int li = 0; li < 32; ++li) {
        int ll = wv * 32 + li;
        const float* per = pe + (size_t)(b * 128 + ll) * 512 + ln * 8;
        floatx4 p0 = *(const floatx4*)per;
        floatx4 p1 = *(const floatx4*)(per + 4);
        float s = 0.f;
#pragma unroll
        for (int j = 0; j < 4; ++j) s += vw0[j] * tanh_f(ph0[j] + p0[j]);
#pragma unroll
        for (int j = 0; j < 4; ++j) s += vw1[j] * tanh_f(ph1[j] + p1[j]);
#pragma unroll
        for (int off = 32; off; off >>= 1) s += __shfl_xor(s, off, 64);
        if (ln == 0) logits[((size_t)t * 128 + ll) * 16 + b] = s;
    }
}

// 6. softmax over b (axis=1 of (T,B,L)) -> att_bf16[b][t][l]
__global__ void att_kernel(const float* logits, unsigned short* attb) {
    int t = blockIdx.x, l = threadIdx.x;     // 128 threads
    const float* p = logits + ((size_t)t * 128 + l) * 16;
    float x[16], mx = -1e30f;
#pragma unroll
    for (int j = 0; j < 16; ++j) { x[j] = p[j]; mx = fmaxf(mx, x[j]); }
    float s = 0.f;
#pragma unroll
    for (int j = 0; j < 16; ++j) { x[j] = __expf(x[j] - mx); s += x[j]; }
    float inv = __builtin_amdgcn_rcpf(s);
#pragma unroll
    for (int j = 0; j < 16; ++j)
        attb[((size_t)j * 128 + t) * 128 + l] = f2bf(x[j] * inv);
}

// 7. weighted[b][t][h] = att[b] @ enc[b]  ->  G[b*128+t][512+h]
__global__ void weighted_kernel(const unsigned short* attb, const unsigned short* enctb,
                                unsigned short* Gmat) {
    int b = blockIdx.z;
    floatx4 acc[4] = {{0,0,0,0},{0,0,0,0},{0,0,0,0},{0,0,0,0}};
    int m0 = blockIdx.x * 64, n0 = blockIdx.y * 64;
    gemm64_acc(attb + (size_t)b * 128 * 128, enctb + (size_t)b * 512 * 128,
               m0, n0, 128, 128, 4, acc);
    int tid = threadIdx.x, wv = tid >> 6, ln = tid & 63, colL = ln & 15, q = ln >> 4;
    int mrow = m0 + wv * 16;
#pragma unroll
    for (int nt = 0; nt < 4; ++nt) {
        int col = n0 + nt * 16 + colL;
#pragma unroll
        for (int r = 0; r < 4; ++r)
            Gmat[(size_t)(b * 128 + mrow + q * 4 + r) * KFC + 512 + col] = f2bf(acc[nt][r]);
    }
}

// ============================================================================
// 8. fc GEMM (m97-structure) + fused per-row (max, sumexp) partials.
// ============================================================================
__global__ __launch_bounds__(256)
void fc_kernel(const unsigned short* G, const unsigned short* fcWb,
               const float* fcb, float2* partials) {
    __shared__ __align__(16) unsigned short lA[128 * 64];
    __shared__ __align__(16) unsigned short lB[128 * 64];
    __shared__ float2 pbuf[128][2];
    int nwg = blockIdx.x;            // 0..249
    int mwg = blockIdx.y;            // 0..15
    int n_base = nwg * 128, m_base = mwg * 128;
    int tid = threadIdx.x, wv = tid >> 6, l = tid & 63;
    int wr = wv >> 1, wc = wv & 1;
    int colL = l & 15, q16 = l >> 4, koff = q16 * 8;
    int srow = l >> 3, scol = (l & 7) * 8;     // staging sub-pattern per chunk

    floatx4 acc[4][4];
#pragma unroll
    for (int i = 0; i < 4; ++i)
#pragma unroll
        for (int j = 0; j < 4; ++j) acc[i][j] = (floatx4){0, 0, 0, 0};

    const unsigned short* gA = G    + (size_t)m_base * KFC;
    const unsigned short* gB = fcWb + (size_t)n_base * KFC;

    for (int kt = 0; kt < 16; ++kt) {
        if (kt) __syncthreads();     // previous tile's reads done before overwrite
        int k0 = kt * 64;
#pragma unroll
        for (int j = 0; j < 4; ++j) {
            int c = wv * 4 + j;
            const unsigned short* ga = gA + (size_t)(c * 8 + srow) * KFC + k0 + scol;
            const unsigned short* gb = gB + (size_t)(c * 8 + srow) * KFC + k0 + scol;
            GLD16(ga, lA + c * 512);
            GLD16(gb, lB + c * 512);
        }
        __syncthreads();             // barrier drains vmcnt -> tiles resident
#pragma unroll
        for (int ks = 0; ks < 2; ++ks) {
            const unsigned short* ap = lA + (wr * 64 + colL) * 64 + ks * 32 + koff;
            const unsigned short* bp = lB + (wc * 64 + colL) * 64 + ks * 32 + koff;
            short8 aF[4], bF[4];
#pragma unroll
            for (int ma = 0; ma < 4; ++ma) aF[ma] = ld8(ap + ma * 16 * 64);
#pragma unroll
            for (int nb = 0; nb < 4; ++nb) bF[nb] = ld8(bp + nb * 16 * 64);
#pragma unroll
            for (int ma = 0; ma < 4; ++ma)
#pragma unroll
                for (int nb = 0; nb < 4; ++nb)
                    acc[ma][nb] = mfma16(aF[ma], bF[nb], acc[ma][nb]);
        }
    }

    // ---- epilogue: per-row (max, sumexp) over this WG's 128 cols ----
    float cb[4];
#pragma unroll
    for (int nb = 0; nb < 4; ++nb)
        cb[nb] = fcb[n_base + wc * 64 + nb * 16 + colL];

#pragma unroll
    for (int ma = 0; ma < 4; ++ma) {
#pragma unroll
        for (int r = 0; r < 4; ++r) {
            float v0 = acc[ma][0][r] + cb[0];
            float v1 = acc[ma][1][r] + cb[1];
            float v2 = acc[ma][2][r] + cb[2];
            float v3 = acc[ma][3][r] + cb[3];
            float M = fmaxf(fmaxf(v0, v1), fmaxf(v2, v3));
#pragma unroll
            for (int off = 1; off < 16; off <<= 1) M = fmaxf(M, __shfl_xor(M, off, 64));
            float e = __expf(v0 - M) + __expf(v1 - M) + __expf(v2 - M) + __expf(v3 - M);
#pragma unroll
            for (int off = 1; off < 16; off <<= 1) e += __shfl_xor(e, off, 64);
            if (colL == 0)
                pbuf[wr * 64 + ma * 16 + q16 * 4 + r][wc] = make_float2(M, e);
        }
    }
    __syncthreads();
    if (tid < 128) {    // merge the two col-halves, write global partial
        float2 a = pbuf[tid][0], b = pbuf[tid][1];
        float M = fmaxf(a.x, b.x);
        float S = a.y * __expf(a.x - M) + b.y * __expf(b.x - M);
        partials[(size_t)(m_base + tid) * 250 + nwg] = make_float2(M, S);
    }
}

// 9. target logit per row: z_y = G[r] . fc_W[y] + fc_b[y]
__global__ void tgt_kernel(const unsigned short* G, const float* fcW, const float* fcb,
                           const int* X, float* tgt) {
    int r = blockIdx.x * 4 + (threadIdx.x >> 6);
    int ln = threadIdx.x & 63;
    int b = r >> 7, t = r & 127;
    int y = X[b * 129 + t + 1];
    y = (y < 0) ? 0 : ((y >= VOCAB) ? VOCAB - 1 : y);   // defensive
    const unsigned short* g = G + (size_t)r * KFC;
    const float* w = fcW + (size_t)y * KFC;
    float s = 0.f;
    for (int j = ln; j < KFC; j += 64) s += bf2f(g[j]) * w[j];
#pragma unroll
    for (int off = 32; off; off >>= 1) s += __shfl_xor(s, off, 64);
    if (ln == 0) tgt[r] = s + fcb[y];
}

// 10. parallel logsumexp merge: 32 lanes per row over 250 partials.
__global__ void row_lse_kernel(const float2* partials, float* lse) {
    int row = blockIdx.x * 8 + (threadIdx.x >> 5);   // 256 blocks x 8 rows
    int ln = threadIdx.x & 31;
    const float2* p = partials + (size_t)row * 250;
    float M = -1e30f, S = 0.f;
    for (int i = ln; i < 250; i += 32) {
        float2 q = p[i];
        float nm = fmaxf(M, q.x);
        S = S * __expf(M - nm) + q.y * __expf(q.x - nm);
        M = nm;
    }
#pragma unroll
    for (int off = 16; off; off >>= 1) {
        float Mo = __shfl_xor(M, off, 64);
        float So = __shfl_xor(S, off, 64);
        float nm = fmaxf(M, Mo);
        S = S * __expf(M - nm) + So * __expf(Mo - nm);
        M = nm;
    }
    if (ln == 0) lse[row] = M + __logf(S);
}

// 11. masked-mean NLL from lse/tgt
__global__ void finalize2_kernel(const float* lse, const float* tgt,
                                 const int* X, float* out) {
    int tid = threadIdx.x;
    float vs = 0.f, vc = 0.f;
    for (int r = tid; r < NROW; r += 256) {
        int b = r >> 7, t = r & 127;
        int y = X[b * 129 + t + 1];
        if (y != 0) { vs += lse[r] - tgt[r]; vc += 1.f; }
    }
    __shared__ float sv[256], sc[256];
    sv[tid] = vs; sc[tid] = vc;
    __syncthreads();
    for (int s = 128; s; s >>= 1) {
        if (tid < s) { sv[tid] += sv[tid + s]; sc[tid] += sc[tid + s]; }
        __syncthreads();
    }
    if (tid == 0) out[0] = sv[0] / sc[0];
}

// ============================================================================
// launcher
// ============================================================================
extern "C" void kernel_launch(void* const* d_in, const int* in_sizes, int n_in,
                              void* d_out, int out_size, void* d_ws, size_t ws_size,
                              hipStream_t stream) {
    const int*   X     = (const int*)d_in[0];
    const float* enc   = (const float*)d_in[2];
    const float* emb   = (const float*)d_in[3];
    const float* Wih0  = (const float*)d_in[4];
    const float* Whh0  = (const float*)d_in[5];
    const float* bih0  = (const float*)d_in[6];
    const float* bhh0  = (const float*)d_in[7];
    const float* Wih1  = (const float*)d_in[8];
    const float* Whh1  = (const float*)d_in[9];
    const float* bih1  = (const float*)d_in[10];
    const float* bhh1  = (const float*)d_in[11];
    const float* attnW = (const float*)d_in[12];
    const float* attnb = (const float*)d_in[13];
    const float* vw    = (const float*)d_in[14];
    const float* fcW   = (const float*)d_in[15];
    const float* fcb   = (const float*)d_in[16];
    const float* h0    = (const float*)d_in[17];
    const float* c0    = (const float*)d_in[18];

    char* ws = (char*)d_ws;
    size_t off = 0;
    auto take = [&](size_t bytes) { char* p = ws + off; off += (bytes + 255) & ~(size_t)255; return p; };
    int*            ctrl    = (int*)           take(12288);
    unsigned short* wih0b   = (unsigned short*)take(2097152);
    unsigned short* whh0b   = (unsigned short*)take(2097152);
    unsigned short* wih1b   = (unsigned short*)take(2097152);
    unsigned short* whh1b   = (unsigned short*)take(2097152);
    unsigned short* whb     = (unsigned short*)take(524288);
    unsigned short* web     = (unsigned short*)take(524288);
    unsigned short* encb    = (unsigned short*)take(2097152);
    unsigned short* enctb   = (unsigned short*)take(2097152);
    unsigned short* xsb     = (unsigned short*)take(2097152);
    unsigned short* h0buf   = (unsigned short*)take(32768);
    unsigned short* h1buf   = (unsigned short*)take(32768);
    unsigned short* A0b     = (unsigned short*)take(8388608);
    unsigned short* hallb   = (unsigned short*)take(2097152);
    unsigned short* gmat    = (unsigned short*)take(4194304);
    float*          ph      = (float*)         take(4194304);
    float*          pe      = (float*)         take(4194304);
    float*          logitsb = (float*)         take(1048576);
    unsigned short* attb    = (unsigned short*)take(524288);
    float2*         parts   = (float2*)        take(4096000);
    float*          tgt     = (float*)         take(8192);
    float*          lseb    = (float*)         take(8192);
    unsigned short* fcWb    = (unsigned short*)take(65536000);
    size_t need = off;
    (void)in_sizes; (void)n_in;

    if (ws_size < need) {
        // Not enough scratch: fail visibly (absmax error) instead of faulting.
        hipLaunchKernelGGL(zero_out_kernel, dim3((out_size + 63) / 64), dim3(64),
                           0, stream, (float*)d_out, out_size);
        return;
    }

    hipLaunchKernelGGL(prep_kernel, dim3(30784), dim3(256), 0, stream,
                       X, enc, emb, Wih0, Whh0, Wih1, Whh1, attnW, h0,
                       wih0b, whh0b, wih1b, whh1b, whb, web, encb, enctb,
                       xsb, h0buf, h1buf, ctrl);
    hipLaunchKernelGGL(a0_kernel, dim3(32, 32), dim3(256), 0, stream,
                       xsb, wih0b, bih0, bhh0, A0b);
    hipLaunchKernelGGL(lstm_kernel, dim3(256), dim3(512), 0, stream,
                       A0b, whh0b, wih1b, whh1b, bih1, bhh1, c0,
                       h0buf, h1buf, hallb, gmat, ctrl, fcW, fcWb);
    hipLaunchKernelGGL(phpe_kernel, dim3(32, 8, 2), dim3(256), 0, stream,
                       hallb, encb, whb, web, attnb, ph, pe);
    hipLaunchKernelGGL(logits_kernel, dim3(2048), dim3(256), 0, stream,
                       ph, pe, vw, logitsb);
    hipLaunchKernelGGL(att_kernel, dim3(128), dim3(128), 0, stream,
                       logitsb, attb);
    hipLaunchKernelGGL(weighted_kernel, dim3(2, 8, 16), dim3(256), 0, stream,
                       attb, enctb, gmat);
    hipLaunchKernelGGL(fc_kernel, dim3(250, 16), dim3(256), 0, stream,
                       gmat, fcWb, fcb, parts);
    hipLaunchKernelGGL(tgt_kernel, dim3(512), dim3(256), 0, stream,
                       gmat, fcW, fcb, X, tgt);
    hipLaunchKernelGGL(row_lse_kernel, dim3(256), dim3(256), 0, stream,
                       parts, lseb);
    hipLaunchKernelGGL(finalize2_kernel, dim3(1), dim3(256), 0, stream,
                       lseb, tgt, X, (float*)d_out);
}

// Round 8
// 973.455 us; speedup vs baseline: 1.9249x; 1.0151x over previous
//
#include <hip/hip_runtime.h>

// ============================================================================
// DecoderGenerator: 2-layer LSTM decoder + additive attention + big vocab
// projection + NLL, fully fused on-device.
//
//   1. prep_kernel     : bf16-cast weights/enc, gather embeddings, transpose
//                        enc, init h-state buffers, zero flags.
//   2. a0_kernel       : A0 = xs @ W_ih0^T + b  (hoisted layer-0 input GEMM)
//   3. lstm_kernel     : persistent kernel, 256 WGs x 512 threads.
//                        WGs 0..31  : ROUND-6 LSTM loop (measured 430us,
//                                     untouched).
//                        WGs 32..255: freeloaders — convert fcW f32->bf16,
//                                     THEN compute pe = enc@We^T + attn_b
//                                     (256 64x64 tiles), all in the LSTM's
//                                     shadow.
//   4. phpe_kernel     : ph = Hall@Wh^T only (z=1; pe moved to freeloaders)
//   5. logits_kernel   : logits[t,b,l] = sum_k v_w[k] tanh(ph+pe)
//   6. att_kernel      : softmax over b (axis=1 of (T,B,L) — per reference!)
//   7. weighted_kernel : weighted = att @ enc  (per-batch GEMM) -> G[:,512:]
//   8. fc_kernel       : m97-structure 128x128xBK64 tiled GEMM + fused
//                        per-row (max,sumexp) partials.
//                        ROUND 13: 1-D grid with bijective XCD-chunked
//                        swizzle, M-major: each XCD keeps the 4MB A matrix
//                        L2-resident and streams each B panel once ->
//                        ~10x less LLC traffic.
//   9. tgt_kernel      : target logits z_y per row
//  10. row_lse_kernel  : parallel 250-way logsumexp merge (32 lanes/row)
//  11. finalize2_kernel: masked-mean NLL from lse/tgt -> d_out[0]
// ============================================================================

#define DI __device__ __forceinline__

typedef __attribute__((ext_vector_type(8))) short short8;
typedef __attribute__((ext_vector_type(4))) float floatx4;
typedef unsigned long long ull;

#define TSEQ   128
#define VOCAB  32000
#define GDIM   2048   // 4*H
#define NROW   2048   // B*T
#define KFC    1024   // 2*H
#define HPAD   520    // LDS row stride for h staging (512 + 8 pad) — ROUND-1

// ---------------- small helpers ----------------
DI float bf2f(unsigned short u) {
    union { unsigned u; float f; } x; x.u = ((unsigned)u) << 16; return x.f;
}
DI unsigned short f2bf(float f) {   // RNE float -> bf16
    unsigned u = __float_as_uint(f);
    unsigned r = (u + 0x7FFF + ((u >> 16) & 1)) >> 16;
    return (unsigned short)r;
}
DI short8 ld8(const unsigned short* p) { return *(const short8*)p; }
DI floatx4 mfma16(short8 a, short8 b, floatx4 c) {
    return __builtin_amdgcn_mfma_f32_16x16x32_bf16(a, b, c, 0, 0, 0);
}
DI float sigm(float x) { return __builtin_amdgcn_rcpf(1.f + __expf(-x)); }
DI float tanh_f(float x) {
    float xc = fminf(8.f, fmaxf(-8.f, x));
    float e  = __expf(2.f * xc);
    return (e - 1.f) * __builtin_amdgcn_rcpf(e + 1.f);
}

// async global -> LDS, 16B per lane. LDS dest must be wave-uniform base;
// lane l writes base + l*16. Global src is per-lane.
#define GLD16(gsrc, ldst)                                                     \
    __builtin_amdgcn_global_load_lds(                                         \
        (const __attribute__((address_space(1))) unsigned int*)(gsrc),        \
        (__attribute__((address_space(3))) unsigned int*)(ldst), 16, 0, 0)

// fallback path: make the failure visible instead of faulting
__global__ void zero_out_kernel(float* out, int n) {
    int i = blockIdx.x * 64 + threadIdx.x;
    if (i < n) out[i] = 0.f;
}

// ============================================================================
// 1. prep kernel : segmented grid-stride over all conversion jobs
// ============================================================================
__global__ void prep_kernel(const int* X, const float* enc, const float* emb,
                            const float* Wih0, const float* Whh0,
                            const float* Wih1, const float* Whh1,
                            const float* attnW, const float* h0,
                            unsigned short* wih0b, unsigned short* whh0b,
                            unsigned short* wih1b, unsigned short* whh1b,
                            unsigned short* whb, unsigned short* web,
                            unsigned short* encb, unsigned short* enctb,
                            unsigned short* xsb,
                            unsigned short* h0buf, unsigned short* h1buf,
                            int* ctrl) {
    if (blockIdx.x == 0) {              // zero all 3072 flag ints
#pragma unroll
        for (int j = 0; j < 12; ++j) ctrl[threadIdx.x + 256 * j] = 0;
    }
    long i = (long)blockIdx.x * 256 + threadIdx.x;
    const long NW = 1048576;
    const long NA = 262144;            // 512x512 half of attn_W
    if (i < NW) { wih0b[i] = f2bf(Wih0[i]); return; } i -= NW;
    if (i < NW) { whh0b[i] = f2bf(Whh0[i]); return; } i -= NW;
    if (i < NW) { wih1b[i] = f2bf(Wih1[i]); return; } i -= NW;
    if (i < NW) { whh1b[i] = f2bf(Whh1[i]); return; } i -= NW;
    if (i < NA) { long k = i >> 9, h = i & 511; whb[i] = f2bf(attnW[k * 1024 + h]);       return; } i -= NA;
    if (i < NA) { long k = i >> 9, h = i & 511; web[i] = f2bf(attnW[k * 1024 + 512 + h]); return; } i -= NA;
    if (i < NW) { encb[i] = f2bf(enc[i]); return; } i -= NW;
    if (i < NW) {  // enc_t[b][h][l] = enc[b][l][h]
        long b = i >> 16, r = i & 65535, h = r >> 7, l = r & 127;
        enctb[i] = f2bf(enc[(b * 128 + l) * 512 + h]); return;
    } i -= NW;
    if (i < NW) {  // xs[t*16+b][e] = emb[X[b][t]][e]
        long m = i >> 9, e = i & 511, t = m >> 4, b = m & 15;
        int xi = X[b * 129 + t];
        xi = (xi < 0) ? 0 : ((xi >= VOCAB) ? VOCAB - 1 : xi);   // defensive
        xsb[i] = f2bf(emb[(long)xi * 512 + e]); return;
    } i -= NW;
    if (i < 16384) {  // h inits into parity-1 buffers
        long layer = i >> 13, r = i & 8191;
        unsigned short v = f2bf(h0[layer * 8192 + r]);
        if (layer == 0) h0buf[8192 + r] = v; else h1buf[8192 + r] = v;
    }
}

// ============================================================================
// shared 64x64 MFMA tile: C[m0..+63][n0..+63] += A(m,k) * B(n,k)^T
// ============================================================================
DI void gemm64_acc(const unsigned short* A, const unsigned short* Bw,
                   int m0, int n0, int lda, int ldb, int nkb, floatx4 acc[4]) {
    int tid = threadIdx.x;
    int wv = tid >> 6, ln = tid & 63;
    int colL = ln & 15, koff = (ln >> 4) * 8;
    const unsigned short* ar  = A  + (size_t)(m0 + wv * 16 + colL) * lda + koff;
    const unsigned short* br0 = Bw + (size_t)(n0 +  0 + colL) * ldb + koff;
    const unsigned short* br1 = Bw + (size_t)(n0 + 16 + colL) * ldb + koff;
    const unsigned short* br2 = Bw + (size_t)(n0 + 32 + colL) * ldb + koff;
    const unsigned short* br3 = Bw + (size_t)(n0 + 48 + colL) * ldb + koff;
    for (int kb = 0; kb < nkb; ++kb) {
        short8 af = ld8(ar + kb * 32);
        acc[0] = mfma16(af, ld8(br0 + kb * 32), acc[0]);
        acc[1] = mfma16(af, ld8(br1 + kb * 32), acc[1]);
        acc[2] = mfma16(af, ld8(br2 + kb * 32), acc[2]);
        acc[3] = mfma16(af, ld8(br3 + kb * 32), acc[3]);
    }
}

// 2. A0 = xs @ W_ih0^T + (b_ih0 + b_hh0), stored bf16 (bias folded)
__global__ void a0_kernel(const unsigned short* xs, const unsigned short* wih0b,
                          const float* bih0, const float* bhh0, unsigned short* A0b) {
    floatx4 acc[4] = {{0,0,0,0},{0,0,0,0},{0,0,0,0},{0,0,0,0}};
    int m0 = blockIdx.x * 64, n0 = blockIdx.y * 64;
    gemm64_acc(xs, wih0b, m0, n0, 512, 512, 16, acc);
    int tid = threadIdx.x, wv = tid >> 6, ln = tid & 63, colL = ln & 15, q = ln >> 4;
    int mrow = m0 + wv * 16;
#pragma unroll
    for (int nt = 0; nt < 4; ++nt) {
        int col = n0 + nt * 16 + colL;
        float bb = bih0[col] + bhh0[col];
#pragma unroll
        for (int r = 0; r < 4; ++r)
            A0b[(size_t)(mrow + q * 4 + r) * GDIM + col] = f2bf(acc[nt][r] + bb);
    }
}

// ============================================================================
// 3. persistent LSTM kernel.  256 WGs x 512 threads.
//    WGs 0..31: ROUND-6 LSTM (430us measured) — untouched.
//    WGs 32..255: freeloaders — fcW f32->bf16, then pe = enc@We^T + attn_b.
// ============================================================================
__global__ __launch_bounds__(512, 1)
void lstm_kernel(const unsigned short* A0b,
                 const unsigned short* whh0b, const unsigned short* wih1b,
                 const unsigned short* whh1b,
                 const float* bih1, const float* bhh1, const float* c0in,
                 unsigned short* h0buf, unsigned short* h1buf,
                 unsigned short* Hall, unsigned short* Gmat, int* flags,
                 const float* fcW, unsigned short* fcWb,
                 const unsigned short* encb, const unsigned short* web,
                 const float* attnb, float* pe) {
    int wg = blockIdx.x;            // 0..255
    int tid = threadIdx.x;          // 0..511

    if (wg >= 32) {
        // -------- freeloader job 1: convert fcW while the LSTM runs --------
        {
            const float4* src = (const float4*)fcW;
            ushort4* dst = (ushort4*)fcWb;
            for (long i = (long)(wg - 32) * 512 + tid; i < 8192000; i += 224 * 512) {
                float4 v = src[i];
                ushort4 o;
                o.x = f2bf(v.x); o.y = f2bf(v.y); o.z = f2bf(v.z); o.w = f2bf(v.w);
                dst[i] = o;
            }
        }
        // -------- freeloader job 2: pe = enc@We^T + attn_b (64x64 tiles) ----
        // 256 tiles; WG supplies two 4-wave groups -> 448 slots, first 256 used.
        {
            int g = tid >> 8, lt = tid & 255;
            int slot = (wg - 32) * 2 + g;
            if (slot < 256) {
                int m0 = (slot >> 3) * 64, n0 = (slot & 7) * 64;
                int wv = lt >> 6, ln = lt & 63;
                int colL = ln & 15, q = ln >> 4, koff = q * 8;
                floatx4 acc[4] = {{0,0,0,0},{0,0,0,0},{0,0,0,0},{0,0,0,0}};
                const unsigned short* ar  = encb + (size_t)(m0 + wv * 16 + colL) * 512 + koff;
                const unsigned short* br0 = web  + (size_t)(n0 +  0 + colL) * 512 + koff;
                const unsigned short* br1 = web  + (size_t)(n0 + 16 + colL) * 512 + koff;
                const unsigned short* br2 = web  + (size_t)(n0 + 32 + colL) * 512 + koff;
                const unsigned short* br3 = web  + (size_t)(n0 + 48 + colL) * 512 + koff;
                for (int kb = 0; kb < 16; ++kb) {
                    short8 af = ld8(ar + kb * 32);
                    acc[0] = mfma16(af, ld8(br0 + kb * 32), acc[0]);
                    acc[1] = mfma16(af, ld8(br1 + kb * 32), acc[1]);
                    acc[2] = mfma16(af, ld8(br2 + kb * 32), acc[2]);
                    acc[3] = mfma16(af, ld8(br3 + kb * 32), acc[3]);
                }
                int mrow = m0 + wv * 16;
#pragma unroll
                for (int nt = 0; nt < 4; ++nt) {
                    int col = n0 + nt * 16 + colL;
                    float bb = attnb[col];
#pragma unroll
                    for (int r = 0; r < 4; ++r)
                        pe[(size_t)(mrow + q * 4 + r) * 512 + col] = acc[nt][r] + bb;
                }
            }
        }
        return;
    }

    __shared__ unsigned short hsh0[16 * HPAD];   // h0[t-1], shared by both halves
    __shared__ unsigned short hsh1[16 * HPAD];   // h1[t-2], L1 half only
    __shared__ float gbuf[2][4][16][16];         // [half][gate][batch][unit]
    int half = tid >> 8;            // 0 = L0, 1 = L1
    int lt   = tid & 255;
    int wv = lt >> 6, ln = lt & 63;
    int u0 = wg * 16;
    int n0 = wv * 512 + u0;         // gate column base (wave-of-half = gate)
    int colL = ln & 15, q = ln >> 4, koff = q * 8;
    int eb = lt >> 4, eu = lt & 15; // elementwise mapping within half
    float c = c0in[half * 8192 + eb * 512 + u0 + eu];
    float bias1 = (half == 1) ? (bih1[n0 + colL] + bhh1[n0 + colL]) : 0.f;

    // ---- one-time: weight slices into registers (128 VGPRs) ----
    short8 wA[16], wB[16];
    if (half == 0) {
        const unsigned short* wr0 = whh0b + (size_t)(n0 + colL) * 512 + koff;
#pragma unroll
        for (int kb = 0; kb < 16; ++kb) wA[kb] = ld8(wr0 + kb * 32);
#pragma unroll
        for (int kb = 0; kb < 16; ++kb) wB[kb] = wA[kb];   // unused, keep defined
    } else {
        const unsigned short* wr1 = wih1b + (size_t)(n0 + colL) * 512 + koff;
        const unsigned short* wr2 = whh1b + (size_t)(n0 + colL) * 512 + koff;
#pragma unroll
        for (int kb = 0; kb < 16; ++kb) wA[kb] = ld8(wr1 + kb * 32);
#pragma unroll
        for (int kb = 0; kb < 16; ++kb) wB[kb] = ld8(wr2 + kb * 32);
    }

    // A0 prefetch for tick 0 (L0 half)
    floatx4 a0pre = {0, 0, 0, 0};
    if (half == 0) {
        const unsigned short* a0r = A0b + (size_t)0 * GDIM + n0 + colL;
        a0pre[0] = bf2f(a0r[(q * 4 + 0) * GDIM]);
        a0pre[1] = bf2f(a0r[(q * 4 + 1) * GDIM]);
        a0pre[2] = bf2f(a0r[(q * 4 + 2) * GDIM]);
        a0pre[3] = bf2f(a0r[(q * 4 + 3) * GDIM]);
    }

    // staging geometry: flat = tid*16 over [16][512]: row = tid>>5,
    // col = (tid&31)*16. 32B/thread.
    int srow = tid >> 5;
    int scol = (tid & 31) << 4;
    unsigned long long* d0 = (unsigned long long*)&hsh0[srow * HPAD + scol];
    unsigned long long* d1 = (unsigned long long*)&hsh1[srow * HPAD + scol];

#pragma unroll 1
    for (int t = 0; t <= TSEQ; ++t) {
        bool actL0 = (t < TSEQ);
        bool actL1 = (t >= 1);
        // ---- stage h vectors LLC -> LDS (relaxed agent atomics, 16KB each) ----
        {
            const unsigned long long* s0 =
                (const unsigned long long*)(h0buf + ((t - 1) & 1) * 8192) + (size_t)tid * 4;
            unsigned long long v0 = __hip_atomic_load(s0 + 0, __ATOMIC_RELAXED, __HIP_MEMORY_SCOPE_AGENT);
            unsigned long long v1 = __hip_atomic_load(s0 + 1, __ATOMIC_RELAXED, __HIP_MEMORY_SCOPE_AGENT);
            unsigned long long v2 = __hip_atomic_load(s0 + 2, __ATOMIC_RELAXED, __HIP_MEMORY_SCOPE_AGENT);
            unsigned long long v3 = __hip_atomic_load(s0 + 3, __ATOMIC_RELAXED, __HIP_MEMORY_SCOPE_AGENT);
            if (actL1) {
                const unsigned long long* s1 =
                    (const unsigned long long*)(h1buf + ((t - 2) & 1) * 8192) + (size_t)tid * 4;
                unsigned long long w0 = __hip_atomic_load(s1 + 0, __ATOMIC_RELAXED, __HIP_MEMORY_SCOPE_AGENT);
                unsigned long long w1 = __hip_atomic_load(s1 + 1, __ATOMIC_RELAXED, __HIP_MEMORY_SCOPE_AGENT);
                unsigned long long w2 = __hip_atomic_load(s1 + 2, __ATOMIC_RELAXED, __HIP_MEMORY_SCOPE_AGENT);
                unsigned long long w3 = __hip_atomic_load(s1 + 3, __ATOMIC_RELAXED, __HIP_MEMORY_SCOPE_AGENT);
                d0[0] = v0; d0[1] = v1; d0[2] = v2; d0[3] = v3;
                d1[0] = w0; d1[1] = w1; d1[2] = w2; d1[3] = w3;
            } else {
                d0[0] = v0; d0[1] = v1; d0[2] = v2; d0[3] = v3;
            }
        }
        __syncthreads();
        // ---- MFMA: LDS fragments x register weights ----
        bool act = half ? actL1 : actL0;
        if (act) {
            floatx4 acc;
            const unsigned short* hl0 = hsh0 + colL * HPAD + koff;
            if (half == 0) {
                acc = a0pre;
#pragma unroll
                for (int kb = 0; kb < 16; ++kb)
                    acc = mfma16(ld8(hl0 + kb * 32), wA[kb], acc);
            } else {
                acc[0] = bias1; acc[1] = bias1; acc[2] = bias1; acc[3] = bias1;
                const unsigned short* hl1 = hsh1 + colL * HPAD + koff;
#pragma unroll
                for (int kb = 0; kb < 16; ++kb)
                    acc = mfma16(ld8(hl0 + kb * 32), wA[kb], acc);
#pragma unroll
                for (int kb = 0; kb < 16; ++kb)
                    acc = mfma16(ld8(hl1 + kb * 32), wB[kb], acc);
            }
            // D layout: row = batch = q*4+r, col = unit = colL
            gbuf[half][wv][q * 4 + 0][colL] = acc[0];
            gbuf[half][wv][q * 4 + 1][colL] = acc[1];
            gbuf[half][wv][q * 4 + 2][colL] = acc[2];
            gbuf[half][wv][q * 4 + 3][colL] = acc[3];
        }
        __syncthreads();
        if (act) {
            float gi = gbuf[half][0][eb][eu], gf = gbuf[half][1][eb][eu];
            float gg = gbuf[half][2][eb][eu], go = gbuf[half][3][eb][eu];
            float c2 = sigm(gf) * c + sigm(gi) * tanh_f(gg);
            float h2 = sigm(go) * tanh_f(c2);
            c = c2;
            unsigned hb = (unsigned)f2bf(h2);
            unsigned up = __shfl_down(hb, 1, 64);
            unsigned packed = hb | (up << 16);
            if ((eu & 1) == 0) {
                if (half == 0) {
                    __hip_atomic_store(
                        (unsigned*)(h0buf + (t & 1) * 8192 + eb * 512 + u0 + eu),
                        packed, __ATOMIC_RELAXED, __HIP_MEMORY_SCOPE_AGENT);
                } else {
                    int s = t - 1;
                    __hip_atomic_store(
                        (unsigned*)(h1buf + (s & 1) * 8192 + eb * 512 + u0 + eu),
                        packed, __ATOMIC_RELAXED, __HIP_MEMORY_SCOPE_AGENT);
                    *(unsigned*)&Hall[(size_t)(s * 16 + eb) * 512 + u0 + eu] = packed;
                    *(unsigned*)&Gmat[(size_t)(eb * 128 + s) * KFC + u0 + eu] = packed;
                }
            }
        }
        if (t < TSEQ) {
            // publish: __syncthreads drains all waves' vmem (hipcc emits
            // s_waitcnt vmcnt(0) before s_barrier) -> h-stores LLC-visible.
            __syncthreads();
            if (tid == 0)
                __hip_atomic_store(flags + wg * 32, t + 1,
                                   __ATOMIC_RELAXED, __HIP_MEMORY_SCOPE_AGENT);
            // prefetch next tick's A0 now — stays in flight to its use.
            if (half == 0 && t + 1 < TSEQ) {
                const unsigned short* a0r = A0b + (size_t)((t + 1) * 16) * GDIM + n0 + colL;
                a0pre[0] = bf2f(a0r[(q * 4 + 0) * GDIM]);
                a0pre[1] = bf2f(a0r[(q * 4 + 1) * GDIM]);
                a0pre[2] = bf2f(a0r[(q * 4 + 2) * GDIM]);
                a0pre[3] = bf2f(a0r[(q * 4 + 3) * GDIM]);
            }
            // ALL threads poll. Thread tid polls WG (tid&31) — exactly the
            // producer of the chunk it stages next iteration.
            {
                int* f = flags + (tid & 31) * 32;
                int g = 0;
                while (__hip_atomic_load(f, __ATOMIC_RELAXED,
                                         __HIP_MEMORY_SCOPE_AGENT) < t + 1) {
                    __builtin_amdgcn_s_sleep(1);
                    if (++g > (1 << 22)) break;   // fail loud, not hung
                }
                asm volatile("" ::: "memory");    // no load hoisting past poll
            }
        }
    }
}

// 4. ph = Hall @ Wh^T   (pe computed by lstm freeloaders)
__global__ void phpe_kernel(const unsigned short* Hall, const unsigned short* encb,
                            const unsigned short* whb, const unsigned short* web,
                            const float* attnb, float* ph, float* pe) {
    bool ispe = (blockIdx.z != 0);
    const unsigned short* A  = ispe ? encb : Hall;
    const unsigned short* Bw = ispe ? web  : whb;
    float* out = ispe ? pe : ph;
    floatx4 acc[4] = {{0,0,0,0},{0,0,0,0},{0,0,0,0},{0,0,0,0}};
    int m0 = blockIdx.x * 64, n0 = blockIdx.y * 64;
    gemm64_acc(A, Bw, m0, n0, 512, 512, 16, acc);
    int tid = threadIdx.x, wv = tid >> 6, ln = tid & 63, colL = ln & 15, q = ln >> 4;
    int mrow = m0 + wv * 16;
#pragma unroll
    for (int nt = 0; nt < 4; ++nt) {
        int col = n0 + nt * 16 + colL;
        float bb = ispe ? attnb[col] : 0.f;
#pragma unroll
        for (int r = 0; r < 4; ++r)
            out[(size_t)(mrow + q * 4 + r) * 512 + col] = acc[nt][r] + bb;
    }
}

// 5. logits[t][l][b] = sum_k v_w[k] * tanh(ph[t*16+b][k] + pe[b*128+l][k])
__global__ void logits_kernel(const float* ph, const float* pe, const float* vw,
                              float* logits) {
    int m = blockIdx.x;             // t*16+b
    int t = m >> 4, b = m & 15;
    int tid = threadIdx.x, wv = tid >> 6, ln = tid & 63;
    const float* phr = ph + (size_t)m * 512 + ln * 8;
    floatx4 ph0 = *(const floatx4*)phr;
    floatx4 ph1 = *(const floatx4*)(phr + 4);
    const float* vwr = vw + ln * 8;
    floatx4 vw0 = *(const floatx4*)vwr;
    floatx4 vw1 = *(const floatx4*)(vwr + 4);
    for (int li = 0; li < 32; ++li) {
        int ll = wv * 32 + li;
        const float* per = pe + (size_t)(b * 128 + ll) * 512 + ln * 8;
        floatx4 p0 = *(const floatx4*)per;
        floatx4 p1 = *(const floatx4*)(per + 4);
        float s = 0.f;
#pragma unroll
        for (int j = 0; j < 4; ++j) s += vw0[j] * tanh_f(ph0[j] + p0[j]);
#pragma unroll
        for (int j = 0; j < 4; ++j) s += vw1[j] * tanh_f(ph1[j] + p1[j]);
#pragma unroll
        for (int off = 32; off; off >>= 1) s += __shfl_xor(s, off, 64);
        if (ln == 0) logits[((size_t)t * 128 + ll) * 16 + b] = s;
    }
}

// 6. softmax over b (axis=1 of (T,B,L)) -> att_bf16[b][t][l]
__global__ void att_kernel(const float* logits, unsigned short* attb) {
    int t = blockIdx.x, l = threadIdx.x;     // 128 threads
    const float* p = logits + ((size_t)t * 128 + l) * 16;
    float x[16], mx = -1e30f;
#pragma unroll
    for (int j = 0; j < 16; ++j) { x[j] = p[j]; mx = fmaxf(mx, x[j]); }
    float s = 0.f;
#pragma unroll
    for (int j = 0; j < 16; ++j) { x[j] = __expf(x[j] - mx); s += x[j]; }
    float inv = __builtin_amdgcn_rcpf(s);
#pragma unroll
    for (int j = 0; j < 16; ++j)
        attb[((size_t)j * 128 + t) * 128 + l] = f2bf(x[j] * inv);
}

// 7. weighted[b][t][h] = att[b] @ enc[b]  ->  G[b*128+t][512+h]
__global__ void weighted_kernel(const unsigned short* attb, const unsigned short* enctb,
                                unsigned short* Gmat) {
    int b = blockIdx.z;
    floatx4 acc[4] = {{0,0,0,0},{0,0,0,0},{0,0,0,0},{0,0,0,0}};
    int m0 = blockIdx.x * 64, n0 = blockIdx.y * 64;
    gemm64_acc(attb + (size_t)b * 128 * 128, enctb + (size_t)b * 512 * 128,
               m0, n0, 128, 128, 4, acc);
    int tid = threadIdx.x, wv = tid >> 6, ln = tid & 63, colL = ln & 15, q = ln >> 4;
    int mrow = m0 + wv * 16;
#pragma unroll
    for (int nt = 0; nt < 4; ++nt) {
        int col = n0 + nt * 16 + colL;
#pragma unroll
        for (int r = 0; r < 4; ++r)
            Gmat[(size_t)(b * 128 + mrow + q * 4 + r) * KFC + 512 + col] = f2bf(acc[nt][r]);
    }
}

// ============================================================================
// 8. fc GEMM (m97-structure) + fused per-row (max, sumexp) partials.
//    ROUND 13: 1-D grid, bijective XCD-chunked swizzle, M-major:
//      orig 0..3999 -> wgid = (orig&7)*500 + (orig>>3)
//      mwg = wgid & 15 (fast), nwg = wgid >> 4
//    Each XCD processes all 16 M-tiles per B-panel consecutively: the 4MB
//    A matrix (G) stays L2-resident per XCD; each 256KB B panel is read
//    once per XCD instead of 16x from LLC.
// ============================================================================
__global__ __launch_bounds__(256)
void fc_kernel(const unsigned short* G, const unsigned short* fcWb,
               const float* fcb, float2* partials) {
    __shared__ __align__(16) unsigned short lA[128 * 64];
    __shared__ __align__(16) unsigned short lB[128 * 64];
    __shared__ float2 pbuf[128][2];
    int orig = blockIdx.x;               // 0..3999
    int wgid = (orig & 7) * 500 + (orig >> 3);   // XCD-chunked, bijective
    int mwg = wgid & 15;                 // 16 M-tiles (fast within XCD)
    int nwg = wgid >> 4;                 // 250 N-tiles
    int n_base = nwg * 128, m_base = mwg * 128;
    int tid = threadIdx.x, wv = tid >> 6, l = tid & 63;
    int wr = wv >> 1, wc = wv & 1;
    int colL = l & 15, q16 = l >> 4, koff = q16 * 8;
    int srow = l >> 3, scol = (l & 7) * 8;     // staging sub-pattern per chunk

    floatx4 acc[4][4];
#pragma unroll
    for (int i = 0; i < 4; ++i)
#pragma unroll
        for (int j = 0; j < 4; ++j) acc[i][j] = (floatx4){0, 0, 0, 0};

    const unsigned short* gA = G    + (size_t)m_base * KFC;
    const unsigned short* gB = fcWb + (size_t)n_base * KFC;

    for (int kt = 0; kt < 16; ++kt) {
        if (kt) __syncthreads();     // previous tile's reads done before overwrite
        int k0 = kt * 64;
#pragma unroll
        for (int j = 0; j < 4; ++j) {
            int c = wv * 4 + j;
            const unsigned short* ga = gA + (size_t)(c * 8 + srow) * KFC + k0 + scol;
            const unsigned short* gb = gB + (size_t)(c * 8 + srow) * KFC + k0 + scol;
            GLD16(ga, lA + c * 512);
            GLD16(gb, lB + c * 512);
        }
        __syncthreads();             // barrier drains vmcnt -> tiles resident
#pragma unroll
        for (int ks = 0; ks < 2; ++ks) {
            const unsigned short* ap = lA + (wr * 64 + colL) * 64 + ks * 32 + koff;
            const unsigned short* bp = lB + (wc * 64 + colL) * 64 + ks * 32 + koff;
            short8 aF[4], bF[4];
#pragma unroll
            for (int ma = 0; ma < 4; ++ma) aF[ma] = ld8(ap + ma * 16 * 64);
#pragma unroll
            for (int nb = 0; nb < 4; ++nb) bF[nb] = ld8(bp + nb * 16 * 64);
#pragma unroll
            for (int ma = 0; ma < 4; ++ma)
#pragma unroll
                for (int nb = 0; nb < 4; ++nb)
                    acc[ma][nb] = mfma16(aF[ma], bF[nb], acc[ma][nb]);
        }
    }

    // ---- epilogue: per-row (max, sumexp) over this WG's 128 cols ----
    float cb[4];
#pragma unroll
    for (int nb = 0; nb < 4; ++nb)
        cb[nb] = fcb[n_base + wc * 64 + nb * 16 + colL];

#pragma unroll
    for (int ma = 0; ma < 4; ++ma) {
#pragma unroll
        for (int r = 0; r < 4; ++r) {
            float v0 = acc[ma][0][r] + cb[0];
            float v1 = acc[ma][1][r] + cb[1];
            float v2 = acc[ma][2][r] + cb[2];
            float v3 = acc[ma][3][r] + cb[3];
            float M = fmaxf(fmaxf(v0, v1), fmaxf(v2, v3));
#pragma unroll
            for (int off = 1; off < 16; off <<= 1) M = fmaxf(M, __shfl_xor(M, off, 64));
            float e = __expf(v0 - M) + __expf(v1 - M) + __expf(v2 - M) + __expf(v3 - M);
#pragma unroll
            for (int off = 1; off < 16; off <<= 1) e += __shfl_xor(e, off, 64);
            if (colL == 0)
                pbuf[wr * 64 + ma * 16 + q16 * 4 + r][wc] = make_float2(M, e);
        }
    }
    __syncthreads();
    if (tid < 128) {    // merge the two col-halves, write global partial
        float2 a = pbuf[tid][0], b = pbuf[tid][1];
        float M = fmaxf(a.x, b.x);
        float S = a.y * __expf(a.x - M) + b.y * __expf(b.x - M);
        partials[(size_t)(m_base + tid) * 250 + nwg] = make_float2(M, S);
    }
}

// 9. target logit per row: z_y = G[r] . fc_W[y] + fc_b[y]
__global__ void tgt_kernel(const unsigned short* G, const float* fcW, const float* fcb,
                           const int* X, float* tgt) {
    int r = blockIdx.x * 4 + (threadIdx.x >> 6);
    int ln = threadIdx.x & 63;
    int b = r >> 7, t = r & 127;
    int y = X[b * 129 + t + 1];
    y = (y < 0) ? 0 : ((y >= VOCAB) ? VOCAB - 1 : y);   // defensive
    const unsigned short* g = G + (size_t)r * KFC;
    const float* w = fcW + (size_t)y * KFC;
    float s = 0.f;
    for (int j = ln; j < KFC; j += 64) s += bf2f(g[j]) * w[j];
#pragma unroll
    for (int off = 32; off; off >>= 1) s += __shfl_xor(s, off, 64);
    if (ln == 0) tgt[r] = s + fcb[y];
}

// 10. parallel logsumexp merge: 32 lanes per row over 250 partials.
__global__ void row_lse_kernel(const float2* partials, float* lse) {
    int row = blockIdx.x * 8 + (threadIdx.x >> 5);   // 256 blocks x 8 rows
    int ln = threadIdx.x & 31;
    const float2* p = partials + (size_t)row * 250;
    float M = -1e30f, S = 0.f;
    for (int i = ln; i < 250; i += 32) {
        float2 q = p[i];
        float nm = fmaxf(M, q.x);
        S = S * __expf(M - nm) + q.y * __expf(q.x - nm);
        M = nm;
    }
#pragma unroll
    for (int off = 16; off; off >>= 1) {
        float Mo = __shfl_xor(M, off, 64);
        float So = __shfl_xor(S, off, 64);
        float nm = fmaxf(M, Mo);
        S = S * __expf(M - nm) + So * __expf(Mo - nm);
        M = nm;
    }
    if (ln == 0) lse[row] = M + __logf(S);
}

// 11. masked-mean NLL from lse/tgt
__global__ void finalize2_kernel(const float* lse, const float* tgt,
                                 const int* X, float* out) {
    int tid = threadIdx.x;
    float vs = 0.f, vc = 0.f;
    for (int r = tid; r < NROW; r += 256) {
        int b = r >> 7, t = r & 127;
        int y = X[b * 129 + t + 1];
        if (y != 0) { vs += lse[r] - tgt[r]; vc += 1.f; }
    }
    __shared__ float sv[256], sc[256];
    sv[tid] = vs; sc[tid] = vc;
    __syncthreads();
    for (int s = 128; s; s >>= 1) {
        if (tid < s) { sv[tid] += sv[tid + s]; sc[tid] += sc[tid + s]; }
        __syncthreads();
    }
    if (tid == 0) out[0] = sv[0] / sc[0];
}

// ============================================================================
// launcher
// ============================================================================
extern "C" void kernel_launch(void* const* d_in, const int* in_sizes, int n_in,
                              void* d_out, int out_size, void* d_ws, size_t ws_size,
                              hipStream_t stream) {
    const int*   X     = (const int*)d_in[0];
    const float* enc   = (const float*)d_in[2];
    const float* emb   = (const float*)d_in[3];
    const float* Wih0  = (const float*)d_in[4];
    const float* Whh0  = (const float*)d_in[5];
    const float* bih0  = (const float*)d_in[6];
    const float* bhh0  = (const float*)d_in[7];
    const float* Wih1  = (const float*)d_in[8];
    const float* Whh1  = (const float*)d_in[9];
    const float* bih1  = (const float*)d_in[10];
    const float* bhh1  = (const float*)d_in[11];
    const float* attnW = (const float*)d_in[12];
    const float* attnb = (const float*)d_in[13];
    const float* vw    = (const float*)d_in[14];
    const float* fcW   = (const float*)d_in[15];
    const float* fcb   = (const float*)d_in[16];
    const float* h0    = (const float*)d_in[17];
    const float* c0    = (const float*)d_in[18];

    char* ws = (char*)d_ws;
    size_t off = 0;
    auto take = [&](size_t bytes) { char* p = ws + off; off += (bytes + 255) & ~(size_t)255; return p; };
    int*            ctrl    = (int*)           take(12288);
    unsigned short* wih0b   = (unsigned short*)take(2097152);
    unsigned short* whh0b   = (unsigned short*)take(2097152);
    unsigned short* wih1b   = (unsigned short*)take(2097152);
    unsigned short* whh1b   = (unsigned short*)take(2097152);
    unsigned short* whb     = (unsigned short*)take(524288);
    unsigned short* web     = (unsigned short*)take(524288);
    unsigned short* encb    = (unsigned short*)take(2097152);
    unsigned short* enctb   = (unsigned short*)take(2097152);
    unsigned short* xsb     = (unsigned short*)take(2097152);
    unsigned short* h0buf   = (unsigned short*)take(32768);
    unsigned short* h1buf   = (unsigned short*)take(32768);
    unsigned short* A0b     = (unsigned short*)take(8388608);
    unsigned short* hallb   = (unsigned short*)take(2097152);
    unsigned short* gmat    = (unsigned short*)take(4194304);
    float*          ph      = (float*)         take(4194304);
    float*          pe      = (float*)         take(4194304);
    float*          logitsb = (float*)         take(1048576);
    unsigned short* attb    = (unsigned short*)take(524288);
    float2*         parts   = (float2*)        take(4096000);
    float*          tgt     = (float*)         take(8192);
    float*          lseb    = (float*)         take(8192);
    unsigned short* fcWb    = (unsigned short*)take(65536000);
    size_t need = off;
    (void)in_sizes; (void)n_in;

    if (ws_size < need) {
        // Not enough scratch: fail visibly (absmax error) instead of faulting.
        hipLaunchKernelGGL(zero_out_kernel, dim3((out_size + 63) / 64), dim3(64),
                           0, stream, (float*)d_out, out_size);
        return;
    }

    hipLaunchKernelGGL(prep_kernel, dim3(30784), dim3(256), 0, stream,
                       X, enc, emb, Wih0, Whh0, Wih1, Whh1, attnW, h0,
                       wih0b, whh0b, wih1b, whh1b, whb, web, encb, enctb,
                       xsb, h0buf, h1buf, ctrl);
    hipLaunchKernelGGL(a0_kernel, dim3(32, 32), dim3(256), 0, stream,
                       xsb, wih0b, bih0, bhh0, A0b);
    hipLaunchKernelGGL(lstm_kernel, dim3(256), dim3(512), 0, stream,
                       A0b, whh0b, wih1b, whh1b, bih1, bhh1, c0,
                       h0buf, h1buf, hallb, gmat, ctrl, fcW, fcWb,
                       encb, web, attnb, pe);
    hipLaunchKernelGGL(phpe_kernel, dim3(32, 8, 1), dim3(256), 0, stream,
                       hallb, encb, whb, web, attnb, ph, pe);
    hipLaunchKernelGGL(logits_kernel, dim3(2048), dim3(256), 0, stream,
                       ph, pe, vw, logitsb);
    hipLaunchKernelGGL(att_kernel, dim3(128), dim3(128), 0, stream,
                       logitsb, attb);
    hipLaunchKernelGGL(weighted_kernel, dim3(2, 8, 16), dim3(256), 0, stream,
                       attb, enctb, gmat);
    hipLaunchKernelGGL(fc_kernel, dim3(4000), dim3(256), 0, stream,
                       gmat, fcWb, fcb, parts);
    hipLaunchKernelGGL(tgt_kernel, dim3(512), dim3(256), 0, stream,
                       gmat, fcW, fcb, X, tgt);
    hipLaunchKernelGGL(row_lse_kernel, dim3(256), dim3(256), 0, stream,
                       parts, lseb);
    hipLaunchKernelGGL(finalize2_kernel, dim3(1), dim3(256), 0, stream,
                       lseb, tgt, X, (float*)d_out);
}